// Round 10
// baseline (291.433 us; speedup 1.0000x reference)
//
#include <hip/hip_runtime.h>
#include <hip/hip_bf16.h>

// ---------------------------------------------------------------------------
// 2-layer GCN (PyG GCNConv) N=100000, E=3.2M.
// Bucket-sort edges by dst (98 x 1024-node buckets, u32 entries), 3-phase
// parallel CSR build (round-8 config: TILE 4096, CHUNKS 8), then pull-based
// aggregation with algebraic reorder AND channel-sliced gather tables:
//   h1b{0,1} = bf16(dis*(x@W1)) split into 2x 16-ch slices (3.2 MB each)
//   agg1 pass p: gathers slice p (L2-resident) -> tb_p
//   agg2 pass p: gathers tb_p -> s2 channels p
//   out = s2@W2 + b2
// ---------------------------------------------------------------------------

#define NF 128
#define HID 32
#define EMB 64

#define BSHIFT 10
#define BNODES 1024
#define CAP 36864
#define NBUKMAX 128
#define TILE 4096
#define EPT 16
#define CHUNKS 8

typedef float vf4 __attribute__((ext_vector_type(4)));
typedef unsigned vu4 __attribute__((ext_vector_type(4)));

static __device__ __forceinline__ unsigned bf16rne(float f) {
    unsigned u = __float_as_uint(f);
    return (u + 0x7fffu + ((u >> 16) & 1u)) >> 16;
}

// swizzled slot id: all CHUNKS chunks of bucket b share idx%8 == b%8
static __device__ __host__ __forceinline__ int hslot(int b, int c) {
    return ((b >> 3) << 6) | (c << 3) | (b & 7);
}

#define ACC8(v) \
    a0 += __uint_as_float((v).x << 16); a1 += __uint_as_float((v).x & 0xffff0000u); \
    a2 += __uint_as_float((v).y << 16); a3 += __uint_as_float((v).y & 0xffff0000u); \
    a4 += __uint_as_float((v).z << 16); a5 += __uint_as_float((v).z & 0xffff0000u); \
    a6 += __uint_as_float((v).w << 16); a7 += __uint_as_float((v).w & 0xffff0000u);

// --- multisplit into 1024-node dst-buckets; dtype detect fused; per-wave hist ---
__global__ __launch_bounds__(256) void k_part(const void* __restrict__ ei,
                                              unsigned* __restrict__ pairs,
                                              int* __restrict__ bcur,
                                              int* __restrict__ cnt_ovf,
                                              unsigned long long* __restrict__ ovf,
                                              int* __restrict__ ovfcnt,
                                              int E, int nbuk) {
    __shared__ unsigned sEnt[TILE];            // 16 KB
    __shared__ unsigned char sB[TILE];         // 4 KB
    __shared__ int hcntw[4][NBUKMAX];          // per-wave hist -> per-wave base
    __shared__ int lcurw[4][NBUKMAX];
    __shared__ int lstart[NBUKMAX], gbase[NBUKMAX];
    __shared__ int sNZ;
    const int tid = threadIdx.x;
    const int w = tid >> 6;
    const int tile0 = blockIdx.x * TILE;
    if (tile0 >= E) return;
    const int tcnt = min(TILE, E - tile0);

    if (tid == 0) sNZ = 0;
    for (int b = tid; b < 4 * NBUKMAX; b += 256) {
        ((int*)hcntw)[b] = 0;
        ((int*)lcurw)[b] = 0;
    }
    __syncthreads();
    {   // dtype detect on this tile: high words all zero <=> int64
        int i = tile0 + tid;
        if (i < E) {
            unsigned hw = ((const unsigned*)ei)[2 * (size_t)i + 1];
            if (hw) sNZ = 1;   // benign race
        }
    }
    __syncthreads();
    const bool is64 = (sNZ == 0);

    int ms[EPT], md[EPT];
#pragma unroll
    for (int k = 0; k < EPT; ++k) {
        int i = tile0 + k * 256 + tid;
        ms[k] = -1;
        if (i < tile0 + tcnt) {
            int s, d;
            if (is64) {
                const long long* p = (const long long*)ei;
                s = (int)__builtin_nontemporal_load(&p[i]);
                d = (int)__builtin_nontemporal_load(&p[(size_t)E + i]);
            } else {
                const int* p = (const int*)ei;
                s = __builtin_nontemporal_load(&p[i]);
                d = __builtin_nontemporal_load(&p[E + i]);
            }
            ms[k] = s; md[k] = d;
            atomicAdd(&hcntw[w][d >> BSHIFT], 1);
        }
    }
    __syncthreads();

    if (tid < 64) {  // wave 0: sum waves, scan buckets, reserve, per-wave bases
        int i0 = tid * 2, i1 = tid * 2 + 1;
        int c0 = 0, c1 = 0;
        if (i0 < nbuk) { c0 = hcntw[0][i0] + hcntw[1][i0] + hcntw[2][i0] + hcntw[3][i0]; }
        if (i1 < nbuk) { c1 = hcntw[0][i1] + hcntw[1][i1] + hcntw[2][i1] + hcntw[3][i1]; }
        int run = c0 + c1, inc = run;
#pragma unroll
        for (int off = 1; off < 64; off <<= 1) {
            int t2 = __shfl_up(inc, off);
            if (tid >= off) inc += t2;
        }
        int excl = inc - run;
        if (i0 < nbuk) {
            lstart[i0] = excl;
            gbase[i0] = c0 ? atomicAdd(&bcur[i0], c0) : 0;
            int off2 = excl;
#pragma unroll
            for (int ww = 0; ww < 4; ++ww) { int t3 = hcntw[ww][i0]; hcntw[ww][i0] = off2; off2 += t3; }
        }
        if (i1 < nbuk) {
            lstart[i1] = excl + c0;
            gbase[i1] = c1 ? atomicAdd(&bcur[i1], c1) : 0;
            int off2 = excl + c0;
#pragma unroll
            for (int ww = 0; ww < 4; ++ww) { int t3 = hcntw[ww][i1]; hcntw[ww][i1] = off2; off2 += t3; }
        }
    }
    __syncthreads();

#pragma unroll
    for (int k = 0; k < EPT; ++k) {
        if (ms[k] >= 0) {
            int b = md[k] >> BSHIFT;
            int slot = hcntw[w][b] + atomicAdd(&lcurw[w][b], 1);
            sEnt[slot] = ((unsigned)(md[k] & (BNODES - 1)) << 17) | (unsigned)ms[k];
            sB[slot] = (unsigned char)b;
        }
    }
    __syncthreads();

    for (int j = tid; j < tcnt; j += 256) {   // bucket-ordered flush
        unsigned ent = sEnt[j];
        int b = sB[j];
        int g = gbase[b] + (j - lstart[b]);
        if (g < CAP) {
            pairs[(size_t)b * CAP + g] = ent;
        } else {
            int d = (b << BSHIFT) | (int)(ent >> 17);
            int s = (int)(ent & 0x1FFFFu);
            int o = atomicAdd(ovfcnt, 1);
            ovf[o] = ((unsigned long long)(unsigned)d << 32) | (unsigned)s;
            atomicAdd(&cnt_ovf[d], 1);
        }
    }
}

// --- exclusive scan of bucket totals -> bucket CSR bases ---
__global__ void k_bscan(const int* __restrict__ bcur, int* __restrict__ bbase,
                        int* __restrict__ roff, int nbuk, int E, int N) {
    __shared__ int sh[128];
    int t = threadIdx.x;  // blockDim=128, nbuk<=128
    int v = (t < nbuk) ? bcur[t] : 0;
    sh[t] = v;
    __syncthreads();
    for (int off = 1; off < 128; off <<= 1) {
        int add = (t >= off) ? sh[t - off] : 0;
        __syncthreads();
        sh[t] += add;
        __syncthreads();
    }
    if (t < nbuk) bbase[t] = sh[t] - v;
    if (t == 0) roff[N] = E;
}

// --- phase A: per-chunk LDS histogram -> histc[slot][1024] ---
__global__ __launch_bounds__(256) void k_hist(const unsigned* __restrict__ pairs,
                                              const int* __restrict__ bcur,
                                              int* __restrict__ histc, int nbuk) {
    __shared__ int hist[BNODES];
    const int idx = blockIdx.x;
    const int c = (idx >> 3) & 7;
    const int b = (idx & 7) | ((idx >> 6) << 3);
    if (b >= nbuk) return;
    const int tid = threadIdx.x;
    const int nb = min(bcur[b], CAP);
    const int csz = (nb + CHUNKS - 1) / CHUNKS;
    const int i0 = min(nb, c * csz), i1 = min(nb, i0 + csz);
    const unsigned* pp = pairs + (size_t)b * CAP;
    for (int i = tid; i < BNODES; i += 256) hist[i] = 0;
    __syncthreads();
    for (int i = i0 + tid; i < i1; i += 256)
        atomicAdd(&hist[__builtin_nontemporal_load(&pp[i]) >> 17], 1);
    __syncthreads();
    int* outp = histc + ((size_t)idx << 10);
    for (int i = tid; i < BNODES; i += 256) outp[i] = hist[i];
}

// --- phase B: per-bucket node scan -> roff/cursor/dis + chunk bases in histc ---
__global__ __launch_bounds__(256) void k_nscan(int* __restrict__ histc,
                                               const int* __restrict__ bbase,
                                               const int* __restrict__ cnt_ovf,
                                               int* __restrict__ roff,
                                               int* __restrict__ cursor,
                                               float* __restrict__ dis, int N) {
    __shared__ int part[256];
    const int b = blockIdx.x, tid = threadIdx.x;
    const int base = bbase[b];
    int h[4][CHUNKS], stg[4], tv[4];
    int run = 0;
    const int l0 = tid * 4;
#pragma unroll
    for (int k = 0; k < 4; ++k) {
        int l = l0 + k;
        int node = (b << BSHIFT) + l;
        int st = 0;
#pragma unroll
        for (int c = 0; c < CHUNKS; ++c) {
            h[k][c] = histc[((size_t)hslot(b, c) << 10) + l];
            st += h[k][c];
        }
        stg[k] = st;
        int ov = (node < N) ? cnt_ovf[node] : 0;
        tv[k] = st + ov;
        run += tv[k];
    }
    part[tid] = run;
    __syncthreads();
    for (int off = 1; off < 256; off <<= 1) {
        int add = (tid >= off) ? part[tid - off] : 0;
        __syncthreads();
        part[tid] += add;
        __syncthreads();
    }
    int excl = part[tid] - run;
#pragma unroll
    for (int k = 0; k < 4; ++k) {
        int l = l0 + k;
        int node = (b << BSHIFT) + l;
        if (node < N) {
            roff[node] = base + excl;
            cursor[node] = base + excl + stg[k];     // overflow appended after staged
            dis[node] = rsqrtf((float)(tv[k] + 1));  // deg includes self-loop
        }
        int cb = base + excl;
#pragma unroll
        for (int c = 0; c < CHUNKS; ++c) {           // in-place: hist -> chunk base
            int hh = h[k][c];
            histc[((size_t)hslot(b, c) << 10) + l] = cb;
            cb += hh;
        }
        excl += tv[k];
    }
}

// --- phase C: per-chunk scatter into CSR; 4 independent chains/thread ---
__global__ __launch_bounds__(256) void k_scat2(const unsigned* __restrict__ pairs,
                                               const int* __restrict__ bcur,
                                               const int* __restrict__ histc,
                                               int* __restrict__ csr, int nbuk) {
    __shared__ int cbase[BNODES];
    __shared__ int lc[BNODES];
    const int idx = blockIdx.x;
    const int c = (idx >> 3) & 7;
    const int b = (idx & 7) | ((idx >> 6) << 3);
    if (b >= nbuk) return;
    const int tid = threadIdx.x;
    const int nb = min(bcur[b], CAP);
    const int csz = (nb + CHUNKS - 1) / CHUNKS;
    const int i0 = min(nb, c * csz), i1 = min(nb, i0 + csz);
    const unsigned* pp = pairs + (size_t)b * CAP;
    const int* hc = histc + ((size_t)idx << 10);
    for (int i = tid; i < BNODES; i += 256) { cbase[i] = hc[i]; lc[i] = 0; }
    __syncthreads();
    int i = i0 + tid;
    for (; i + 768 < i1; i += 1024) {
        unsigned e0 = pp[i], e1 = pp[i + 256], e2 = pp[i + 512], e3 = pp[i + 768];
        int l0 = e0 >> 17, l1 = e1 >> 17, l2 = e2 >> 17, l3 = e3 >> 17;
        int p0 = cbase[l0] + atomicAdd(&lc[l0], 1);
        int p1 = cbase[l1] + atomicAdd(&lc[l1], 1);
        int p2 = cbase[l2] + atomicAdd(&lc[l2], 1);
        int p3 = cbase[l3] + atomicAdd(&lc[l3], 1);
        csr[p0] = (int)(e0 & 0x1FFFFu);
        csr[p1] = (int)(e1 & 0x1FFFFu);
        csr[p2] = (int)(e2 & 0x1FFFFu);
        csr[p3] = (int)(e3 & 0x1FFFFu);
    }
    for (; i < i1; i += 256) {
        unsigned ent = pp[i];
        int l = ent >> 17;
        int pos = cbase[l] + atomicAdd(&lc[l], 1);
        csr[pos] = (int)(ent & 0x1FFFFu);
    }
}

// --- overflow sweep (empty for benchmark data) ---
__global__ __launch_bounds__(256) void k_ovf(const unsigned long long* __restrict__ ovf,
                                             const int* __restrict__ ovfcnt,
                                             int* __restrict__ cursor,
                                             int* __restrict__ csr) {
    int n = *ovfcnt;
    for (int i = blockIdx.x * 256 + threadIdx.x; i < n; i += 256 * 8) {
        unsigned long long pr = ovf[i];
        int pos = atomicAdd(&cursor[(int)(unsigned)(pr >> 32)], 1);
        csr[pos] = (int)(unsigned)pr;
    }
}

// --- GEMM1: h1b slices = bf16(dis[r] * (x[r] @ W1)), split by 16-ch halves ---
__global__ __launch_bounds__(256) void k_gemm1(const float* __restrict__ x,
                                               const float* __restrict__ W,
                                               const float* __restrict__ dis,
                                               unsigned* __restrict__ h1b0,
                                               unsigned* __restrict__ h1b1, int N) {
    __shared__ float sW[NF * HID];
    __shared__ float sx[32][132];
    const int t = threadIdx.x;
    for (int i = t; i < NF * HID; i += 256) sW[i] = W[i];
    const int row0 = blockIdx.x * 32;
    {
        const float4* xv = (const float4*)(x + (size_t)row0 * NF);
        for (int i = t; i < 32 * 32; i += 256) {
            int r = i >> 5, c = i & 31;
            float4 v = make_float4(0.f, 0.f, 0.f, 0.f);
            if (row0 + r < N) v = xv[(size_t)r * 32 + c];
            *(float4*)&sx[r][c * 4] = v;
        }
    }
    __syncthreads();
    const int col4 = (t & 7) * 4;
    const int row = t >> 3;
    float a0 = 0.f, a1 = 0.f, a2 = 0.f, a3 = 0.f;
#pragma unroll 8
    for (int k = 0; k < NF; ++k) {
        float xs = sx[row][k];
        float4 w = *(const float4*)&sW[k * HID + col4];
        a0 += xs * w.x; a1 += xs * w.y; a2 += xs * w.z; a3 += xs * w.w;
    }
    int r = row0 + row;
    if (r < N) {
        float d = dis[r];
        unsigned u0 = bf16rne(a0 * d) | (bf16rne(a1 * d) << 16);
        unsigned u1 = bf16rne(a2 * d) | (bf16rne(a3 * d) << 16);
        unsigned* dst = ((t & 7) < 4) ? h1b0 : h1b1;    // slice by channel half
        *(uint2*)&dst[(size_t)r * 8 + ((t & 7) & 3) * 2] = make_uint2(u0, u1);
    }
}

// --- agg1 pass over one 16-ch slice: tb_p = bf16(dis*relu(dis*(self+sum)+b1_p))
// 2 lanes/node, uint4 (8 ch)/lane, unroll-8; gather table 3.2 MB (L2-resident)
__global__ __launch_bounds__(256) void k_agg1s(const uint4* __restrict__ hs,
                                               const int* __restrict__ roff,
                                               const int* __restrict__ csr,
                                               const float* __restrict__ dis,
                                               const float* __restrict__ b1p,
                                               uint4* __restrict__ tbp, int N) {
    int tt = blockIdx.x * 256 + threadIdx.x;
    int node = tt >> 1;
    if (node >= N) return;
    int j = tt & 1;
    uint4 u = hs[(size_t)node * 2 + j];         // self-loop
    float a0, a1, a2, a3, a4, a5, a6, a7;
    a0 = __uint_as_float(u.x << 16); a1 = __uint_as_float(u.x & 0xffff0000u);
    a2 = __uint_as_float(u.y << 16); a3 = __uint_as_float(u.y & 0xffff0000u);
    a4 = __uint_as_float(u.z << 16); a5 = __uint_as_float(u.z & 0xffff0000u);
    a6 = __uint_as_float(u.w << 16); a7 = __uint_as_float(u.w & 0xffff0000u);
    int e0 = roff[node], e1 = roff[node + 1];
    int e = e0;
    for (; e + 8 <= e1; e += 8) {
        int s0 = __builtin_nontemporal_load(&csr[e + 0]);
        int s1 = __builtin_nontemporal_load(&csr[e + 1]);
        int s2 = __builtin_nontemporal_load(&csr[e + 2]);
        int s3 = __builtin_nontemporal_load(&csr[e + 3]);
        int s4 = __builtin_nontemporal_load(&csr[e + 4]);
        int s5 = __builtin_nontemporal_load(&csr[e + 5]);
        int s6 = __builtin_nontemporal_load(&csr[e + 6]);
        int s7 = __builtin_nontemporal_load(&csr[e + 7]);
        uint4 v0 = hs[(size_t)s0 * 2 + j];
        uint4 v1 = hs[(size_t)s1 * 2 + j];
        uint4 v2 = hs[(size_t)s2 * 2 + j];
        uint4 v3 = hs[(size_t)s3 * 2 + j];
        uint4 v4 = hs[(size_t)s4 * 2 + j];
        uint4 v5 = hs[(size_t)s5 * 2 + j];
        uint4 v6 = hs[(size_t)s6 * 2 + j];
        uint4 v7 = hs[(size_t)s7 * 2 + j];
        ACC8(v0) ACC8(v1) ACC8(v2) ACC8(v3) ACC8(v4) ACC8(v5) ACC8(v6) ACC8(v7)
    }
    for (; e + 4 <= e1; e += 4) {
        int s0 = __builtin_nontemporal_load(&csr[e + 0]);
        int s1 = __builtin_nontemporal_load(&csr[e + 1]);
        int s2 = __builtin_nontemporal_load(&csr[e + 2]);
        int s3 = __builtin_nontemporal_load(&csr[e + 3]);
        uint4 v0 = hs[(size_t)s0 * 2 + j];
        uint4 v1 = hs[(size_t)s1 * 2 + j];
        uint4 v2 = hs[(size_t)s2 * 2 + j];
        uint4 v3 = hs[(size_t)s3 * 2 + j];
        ACC8(v0) ACC8(v1) ACC8(v2) ACC8(v3)
    }
    for (; e < e1; ++e) {
        int s = __builtin_nontemporal_load(&csr[e]);
        uint4 v = hs[(size_t)s * 2 + j];
        ACC8(v)
    }
    float d = dis[node];
    float4 bb0 = *(const float4*)&b1p[j * 8];
    float4 bb1 = *(const float4*)&b1p[j * 8 + 4];
    float r0 = fmaxf(a0 * d + bb0.x, 0.f) * d, r1 = fmaxf(a1 * d + bb0.y, 0.f) * d;
    float r2 = fmaxf(a2 * d + bb0.z, 0.f) * d, r3 = fmaxf(a3 * d + bb0.w, 0.f) * d;
    float r4 = fmaxf(a4 * d + bb1.x, 0.f) * d, r5 = fmaxf(a5 * d + bb1.y, 0.f) * d;
    float r6 = fmaxf(a6 * d + bb1.z, 0.f) * d, r7 = fmaxf(a7 * d + bb1.w, 0.f) * d;
    uint4 o;
    o.x = bf16rne(r0) | (bf16rne(r1) << 16);
    o.y = bf16rne(r2) | (bf16rne(r3) << 16);
    o.z = bf16rne(r4) | (bf16rne(r5) << 16);
    o.w = bf16rne(r6) | (bf16rne(r7) << 16);
    tbp[(size_t)node * 2 + j] = o;
}

// --- agg2 pass over one 16-ch slice: s2 channels p = dis*(self + sum tb_p) ---
__global__ __launch_bounds__(256) void k_agg2s(const uint4* __restrict__ tbp,
                                               const int* __restrict__ roff,
                                               const int* __restrict__ csr,
                                               const float* __restrict__ dis,
                                               float* __restrict__ s2,
                                               int chbase, int N) {
    int tt = blockIdx.x * 256 + threadIdx.x;
    int node = tt >> 1;
    if (node >= N) return;
    int j = tt & 1;
    uint4 u = tbp[(size_t)node * 2 + j];        // self-loop
    float a0, a1, a2, a3, a4, a5, a6, a7;
    a0 = __uint_as_float(u.x << 16); a1 = __uint_as_float(u.x & 0xffff0000u);
    a2 = __uint_as_float(u.y << 16); a3 = __uint_as_float(u.y & 0xffff0000u);
    a4 = __uint_as_float(u.z << 16); a5 = __uint_as_float(u.z & 0xffff0000u);
    a6 = __uint_as_float(u.w << 16); a7 = __uint_as_float(u.w & 0xffff0000u);
    int e0 = roff[node], e1 = roff[node + 1];
    int e = e0;
    for (; e + 8 <= e1; e += 8) {
        int s0 = __builtin_nontemporal_load(&csr[e + 0]);
        int s1 = __builtin_nontemporal_load(&csr[e + 1]);
        int s2i = __builtin_nontemporal_load(&csr[e + 2]);
        int s3 = __builtin_nontemporal_load(&csr[e + 3]);
        int s4 = __builtin_nontemporal_load(&csr[e + 4]);
        int s5 = __builtin_nontemporal_load(&csr[e + 5]);
        int s6 = __builtin_nontemporal_load(&csr[e + 6]);
        int s7 = __builtin_nontemporal_load(&csr[e + 7]);
        uint4 v0 = tbp[(size_t)s0 * 2 + j];
        uint4 v1 = tbp[(size_t)s1 * 2 + j];
        uint4 v2 = tbp[(size_t)s2i * 2 + j];
        uint4 v3 = tbp[(size_t)s3 * 2 + j];
        uint4 v4 = tbp[(size_t)s4 * 2 + j];
        uint4 v5 = tbp[(size_t)s5 * 2 + j];
        uint4 v6 = tbp[(size_t)s6 * 2 + j];
        uint4 v7 = tbp[(size_t)s7 * 2 + j];
        ACC8(v0) ACC8(v1) ACC8(v2) ACC8(v3) ACC8(v4) ACC8(v5) ACC8(v6) ACC8(v7)
    }
    for (; e + 4 <= e1; e += 4) {
        int s0 = __builtin_nontemporal_load(&csr[e + 0]);
        int s1 = __builtin_nontemporal_load(&csr[e + 1]);
        int s2i = __builtin_nontemporal_load(&csr[e + 2]);
        int s3 = __builtin_nontemporal_load(&csr[e + 3]);
        uint4 v0 = tbp[(size_t)s0 * 2 + j];
        uint4 v1 = tbp[(size_t)s1 * 2 + j];
        uint4 v2 = tbp[(size_t)s2i * 2 + j];
        uint4 v3 = tbp[(size_t)s3 * 2 + j];
        ACC8(v0) ACC8(v1) ACC8(v2) ACC8(v3)
    }
    for (; e < e1; ++e) {
        int s = __builtin_nontemporal_load(&csr[e]);
        uint4 v = tbp[(size_t)s * 2 + j];
        ACC8(v)
    }
    float d = dis[node];
    vf4 o0, o1;
    o0.x = a0 * d; o0.y = a1 * d; o0.z = a2 * d; o0.w = a3 * d;
    o1.x = a4 * d; o1.y = a5 * d; o1.z = a6 * d; o1.w = a7 * d;
    vf4* op = (vf4*)&s2[(size_t)node * HID + chbase + j * 8];
    __builtin_nontemporal_store(o0, op);
    __builtin_nontemporal_store(o1, op + 1);
}

// --- GEMM2: out[r] = s2[r] @ W2 + b2 ---
__global__ __launch_bounds__(256) void k_gemm2(const float* __restrict__ a,
                                               const float* __restrict__ W,
                                               const float* __restrict__ b2,
                                               float* __restrict__ out, int N) {
    __shared__ float sW[HID * EMB];
    __shared__ float sx[32][36];
    const int t = threadIdx.x;
    for (int i = t; i < HID * EMB; i += 256) sW[i] = W[i];
    const int row0 = blockIdx.x * 32;
    {
        const float4* av = (const float4*)(a + (size_t)row0 * HID);
        int r = t >> 3, c = t & 7;
        float4 v = make_float4(0.f, 0.f, 0.f, 0.f);
        if (row0 + r < N) v = av[(size_t)r * 8 + c];
        *(float4*)&sx[r][c * 4] = v;
    }
    __syncthreads();
    const int col4 = (t & 15) * 4;
    const int r0 = t >> 4;
    float a00 = 0.f, a01 = 0.f, a02 = 0.f, a03 = 0.f;
    float a10 = 0.f, a11 = 0.f, a12 = 0.f, a13 = 0.f;
#pragma unroll
    for (int k = 0; k < HID; ++k) {
        float4 w = *(const float4*)&sW[k * EMB + col4];
        float xa = sx[r0][k];
        float xb = sx[r0 + 16][k];
        a00 += xa * w.x; a01 += xa * w.y; a02 += xa * w.z; a03 += xa * w.w;
        a10 += xb * w.x; a11 += xb * w.y; a12 += xb * w.z; a13 += xb * w.w;
    }
    float4 bb = *(const float4*)&b2[col4];
    int ra = row0 + r0, rb = row0 + r0 + 16;
    if (ra < N) {
        vf4 o; o.x = a00 + bb.x; o.y = a01 + bb.y; o.z = a02 + bb.z; o.w = a03 + bb.w;
        __builtin_nontemporal_store(o, (vf4*)&out[(size_t)ra * EMB + col4]);
    }
    if (rb < N) {
        vf4 o; o.x = a10 + bb.x; o.y = a11 + bb.y; o.z = a12 + bb.z; o.w = a13 + bb.w;
        __builtin_nontemporal_store(o, (vf4*)&out[(size_t)rb * EMB + col4]);
    }
}

extern "C" void kernel_launch(void* const* d_in, const int* in_sizes, int n_in,
                              void* d_out, int out_size, void* d_ws, size_t ws_size,
                              hipStream_t stream) {
    const float* x  = (const float*)d_in[0];
    const void*  ei = d_in[1];
    const float* W1 = (const float*)d_in[2];
    const float* b1 = (const float*)d_in[3];
    const float* W2 = (const float*)d_in[4];
    const float* b2 = (const float*)d_in[5];
    float* out = (float*)d_out;

    const int N = in_sizes[0] / NF;              // 100000
    const int E = in_sizes[1] / 2;               // 3200000
    const int nbuk = (N + BNODES - 1) >> BSHIFT; // 98

    char* ws = (char*)d_ws;
    size_t off = 0;
    auto take = [&](size_t bytes) -> void* {
        void* p = ws + off;
        off += (bytes + 255) & ~(size_t)255;
        return p;
    };
    // zeroed region first (single memset)
    int* cnt_ovf = (int*)take((size_t)N * 4);
    int* bcur    = (int*)take((size_t)NBUKMAX * 4);
    int* ovfcnt  = (int*)take(4);
    size_t zbytes = off;
    // rest
    int*                bbase  = (int*)take((size_t)NBUKMAX * 4);
    int*                roff   = (int*)take((size_t)(N + 1) * 4);
    int*                cursor = (int*)take((size_t)N * 4);
    float*              dis    = (float*)take((size_t)N * 4);
    int*                histc  = (int*)take((size_t)NBUKMAX * CHUNKS * BNODES * 4);
    unsigned*           pairs  = (unsigned*)take((size_t)nbuk * CAP * 4);
    unsigned long long* ovf    = (unsigned long long*)take((size_t)E * 8);
    int*                csr    = (int*)take((size_t)E * 4);
    unsigned*           h1b0   = (unsigned*)take((size_t)N * 16 * 2);
    unsigned*           h1b1   = (unsigned*)take((size_t)N * 16 * 2);
    unsigned*           tb0    = (unsigned*)take((size_t)N * 16 * 2);
    unsigned*           tb1    = (unsigned*)take((size_t)N * 16 * 2);
    float*              s2     = (float*)take((size_t)N * HID * 4);

    (void)hipMemsetAsync(cnt_ovf, 0, zbytes, stream);

    const int gridBC = ((nbuk + 7) / 8) * 64;
    const int gridAgg = (int)(((size_t)N * 2 + 255) / 256);

    k_part<<<(E + TILE - 1) / TILE, 256, 0, stream>>>(ei, pairs, bcur, cnt_ovf,
                                                      ovf, ovfcnt, E, nbuk);
    k_bscan<<<1, 128, 0, stream>>>(bcur, bbase, roff, nbuk, E, N);
    k_hist<<<gridBC, 256, 0, stream>>>(pairs, bcur, histc, nbuk);
    k_nscan<<<nbuk, 256, 0, stream>>>(histc, bbase, cnt_ovf, roff, cursor, dis, N);
    k_scat2<<<gridBC, 256, 0, stream>>>(pairs, bcur, histc, csr, nbuk);
    k_ovf<<<8, 256, 0, stream>>>(ovf, ovfcnt, cursor, csr);

    k_gemm1<<<(N + 31) / 32, 256, 0, stream>>>(x, W1, dis, h1b0, h1b1, N);
    k_agg1s<<<gridAgg, 256, 0, stream>>>((const uint4*)h1b0, roff, csr, dis,
                                         b1, (uint4*)tb0, N);
    k_agg1s<<<gridAgg, 256, 0, stream>>>((const uint4*)h1b1, roff, csr, dis,
                                         b1 + 16, (uint4*)tb1, N);
    k_agg2s<<<gridAgg, 256, 0, stream>>>((const uint4*)tb0, roff, csr, dis,
                                         s2, 0, N);
    k_agg2s<<<gridAgg, 256, 0, stream>>>((const uint4*)tb1, roff, csr, dis,
                                         s2, 16, N);
    k_gemm2<<<(N + 31) / 32, 256, 0, stream>>>(s2, W2, b2, out, N);
}

// Round 11
// 231.597 us; speedup vs baseline: 1.2584x; 1.2584x over previous
//
#include <hip/hip_runtime.h>
#include <hip/hip_bf16.h>

// ---------------------------------------------------------------------------
// 2-layer GCN (PyG GCNConv) N=100000, E=3.2M.
// Bucket-sort edges by dst (98 x 1024-node buckets, u32 entries), 3-phase
// parallel CSR build (TILE 4096, CHUNKS 8 = 8 per-bucket sub-regions with
// INDEPENDENT reservation counters, blockIdx%8-keyed -> 8x less atomic
// contention), then pull-based aggregation with algebraic reorder:
//   h1b = bf16(dis*(x@W1));  t = bf16(dis*relu(dis*agg(h1b)+b1))
//   s2  = dis*agg(t);        out = s2@W2 + b2
// ---------------------------------------------------------------------------

#define NF 128
#define HID 32
#define EMB 64

#define BSHIFT 10
#define BNODES 1024
#define CAPS 4608                          // per-sub-region cap (mean 4082 + 8 sigma)
#define CAP (8 * CAPS)                     // 36864 per bucket
#define NBUKMAX 128
#define TILE 4096
#define EPT 16
#define CHUNKS 8

typedef float vf4 __attribute__((ext_vector_type(4)));
typedef unsigned vu4 __attribute__((ext_vector_type(4)));

static __device__ __forceinline__ unsigned bf16rne(float f) {
    unsigned u = __float_as_uint(f);
    return (u + 0x7fffu + ((u >> 16) & 1u)) >> 16;
}

// swizzled slot id: all CHUNKS chunks of bucket b share idx%8 == b%8
static __device__ __host__ __forceinline__ int hslot(int b, int c) {
    return ((b >> 3) << 6) | (c << 3) | (b & 7);
}

#define ACC8(v) \
    a0 += __uint_as_float((v).x << 16); a1 += __uint_as_float((v).x & 0xffff0000u); \
    a2 += __uint_as_float((v).y << 16); a3 += __uint_as_float((v).y & 0xffff0000u); \
    a4 += __uint_as_float((v).z << 16); a5 += __uint_as_float((v).z & 0xffff0000u); \
    a6 += __uint_as_float((v).w << 16); a7 += __uint_as_float((v).w & 0xffff0000u);

// --- multisplit into 1024-node dst-buckets; dtype detect fused; per-wave hist;
//     per-(bucket, blockIdx%8) sub-region reservation ---
__global__ __launch_bounds__(256) void k_part(const void* __restrict__ ei,
                                              unsigned* __restrict__ pairs,
                                              int* __restrict__ bcur8,
                                              int* __restrict__ cnt_ovf,
                                              unsigned long long* __restrict__ ovf,
                                              int* __restrict__ ovfcnt,
                                              int E, int nbuk) {
    __shared__ unsigned sEnt[TILE];            // 16 KB
    __shared__ unsigned char sB[TILE];         // 4 KB
    __shared__ int hcntw[4][NBUKMAX];          // per-wave hist -> per-wave base
    __shared__ int lcurw[4][NBUKMAX];
    __shared__ int lstart[NBUKMAX], gbase[NBUKMAX];
    __shared__ int sNZ;
    const int tid = threadIdx.x;
    const int w = tid >> 6;
    const int grp = blockIdx.x & 7;            // sub-region key
    const int tile0 = blockIdx.x * TILE;
    if (tile0 >= E) return;
    const int tcnt = min(TILE, E - tile0);

    if (tid == 0) sNZ = 0;
    for (int b = tid; b < 4 * NBUKMAX; b += 256) {
        ((int*)hcntw)[b] = 0;
        ((int*)lcurw)[b] = 0;
    }
    __syncthreads();
    {   // dtype detect on this tile: high words all zero <=> int64
        int i = tile0 + tid;
        if (i < E) {
            unsigned hw = ((const unsigned*)ei)[2 * (size_t)i + 1];
            if (hw) sNZ = 1;   // benign race
        }
    }
    __syncthreads();
    const bool is64 = (sNZ == 0);

    int ms[EPT], md[EPT];
#pragma unroll
    for (int k = 0; k < EPT; ++k) {
        int i = tile0 + k * 256 + tid;
        ms[k] = -1;
        if (i < tile0 + tcnt) {
            int s, d;
            if (is64) {
                const long long* p = (const long long*)ei;
                s = (int)__builtin_nontemporal_load(&p[i]);
                d = (int)__builtin_nontemporal_load(&p[(size_t)E + i]);
            } else {
                const int* p = (const int*)ei;
                s = __builtin_nontemporal_load(&p[i]);
                d = __builtin_nontemporal_load(&p[E + i]);
            }
            ms[k] = s; md[k] = d;
            atomicAdd(&hcntw[w][d >> BSHIFT], 1);
        }
    }
    __syncthreads();

    if (tid < 64) {  // wave 0: sum waves, scan buckets, reserve (sub-counter), bases
        int i0 = tid * 2, i1 = tid * 2 + 1;
        int c0 = 0, c1 = 0;
        if (i0 < nbuk) { c0 = hcntw[0][i0] + hcntw[1][i0] + hcntw[2][i0] + hcntw[3][i0]; }
        if (i1 < nbuk) { c1 = hcntw[0][i1] + hcntw[1][i1] + hcntw[2][i1] + hcntw[3][i1]; }
        int run = c0 + c1, inc = run;
#pragma unroll
        for (int off = 1; off < 64; off <<= 1) {
            int t2 = __shfl_up(inc, off);
            if (tid >= off) inc += t2;
        }
        int excl = inc - run;
        if (i0 < nbuk) {
            lstart[i0] = excl;
            gbase[i0] = c0 ? atomicAdd(&bcur8[i0 * 8 + grp], c0) : 0;
            int off2 = excl;
#pragma unroll
            for (int ww = 0; ww < 4; ++ww) { int t3 = hcntw[ww][i0]; hcntw[ww][i0] = off2; off2 += t3; }
        }
        if (i1 < nbuk) {
            lstart[i1] = excl + c0;
            gbase[i1] = c1 ? atomicAdd(&bcur8[i1 * 8 + grp], c1) : 0;
            int off2 = excl + c0;
#pragma unroll
            for (int ww = 0; ww < 4; ++ww) { int t3 = hcntw[ww][i1]; hcntw[ww][i1] = off2; off2 += t3; }
        }
    }
    __syncthreads();

#pragma unroll
    for (int k = 0; k < EPT; ++k) {
        if (ms[k] >= 0) {
            int b = md[k] >> BSHIFT;
            int slot = hcntw[w][b] + atomicAdd(&lcurw[w][b], 1);
            sEnt[slot] = ((unsigned)(md[k] & (BNODES - 1)) << 17) | (unsigned)ms[k];
            sB[slot] = (unsigned char)b;
        }
    }
    __syncthreads();

    for (int j = tid; j < tcnt; j += 256) {   // bucket-ordered flush
        unsigned ent = sEnt[j];
        int b = sB[j];
        int g = gbase[b] + (j - lstart[b]);
        if (g < CAPS) {
            pairs[(size_t)b * CAP + grp * CAPS + g] = ent;
        } else {
            int d = (b << BSHIFT) | (int)(ent >> 17);
            int s = (int)(ent & 0x1FFFFu);
            int o = atomicAdd(ovfcnt, 1);
            ovf[o] = ((unsigned long long)(unsigned)d << 32) | (unsigned)s;
            atomicAdd(&cnt_ovf[d], 1);
        }
    }
}

// --- exclusive scan of bucket totals (sum of 8 sub-counters) -> CSR bases ---
__global__ void k_bscan(const int* __restrict__ bcur8, int* __restrict__ bbase,
                        int* __restrict__ roff, int nbuk, int E, int N) {
    __shared__ int sh[128];
    int t = threadIdx.x;  // blockDim=128, nbuk<=128
    int v = 0;
    if (t < nbuk) {
#pragma unroll
        for (int k = 0; k < 8; ++k) v += bcur8[t * 8 + k];   // true totals (incl ovf)
    }
    sh[t] = v;
    __syncthreads();
    for (int off = 1; off < 128; off <<= 1) {
        int add = (t >= off) ? sh[t - off] : 0;
        __syncthreads();
        sh[t] += add;
        __syncthreads();
    }
    if (t < nbuk) bbase[t] = sh[t] - v;
    if (t == 0) roff[N] = E;
}

// --- phase A: per-sub-region LDS histogram -> histc[slot][1024] ---
__global__ __launch_bounds__(256) void k_hist(const unsigned* __restrict__ pairs,
                                              const int* __restrict__ bcur8,
                                              int* __restrict__ histc, int nbuk) {
    __shared__ int hist[BNODES];
    const int idx = blockIdx.x;
    const int c = (idx >> 3) & 7;
    const int b = (idx & 7) | ((idx >> 6) << 3);
    if (b >= nbuk) return;
    const int tid = threadIdx.x;
    const int nbc = min(bcur8[b * 8 + c], CAPS);     // staged count in sub-region c
    const int i0 = c * CAPS, i1 = i0 + nbc;
    const unsigned* pp = pairs + (size_t)b * CAP;
    for (int i = tid; i < BNODES; i += 256) hist[i] = 0;
    __syncthreads();
    for (int i = i0 + tid; i < i1; i += 256)
        atomicAdd(&hist[__builtin_nontemporal_load(&pp[i]) >> 17], 1);
    __syncthreads();
    int* outp = histc + ((size_t)idx << 10);
    for (int i = tid; i < BNODES; i += 256) outp[i] = hist[i];
}

// --- phase B: per-bucket node scan -> roff/cursor/dis + chunk bases in histc ---
__global__ __launch_bounds__(256) void k_nscan(int* __restrict__ histc,
                                               const int* __restrict__ bbase,
                                               const int* __restrict__ cnt_ovf,
                                               int* __restrict__ roff,
                                               int* __restrict__ cursor,
                                               float* __restrict__ dis, int N) {
    __shared__ int part[256];
    const int b = blockIdx.x, tid = threadIdx.x;
    const int base = bbase[b];
    int h[4][CHUNKS], stg[4], tv[4];
    int run = 0;
    const int l0 = tid * 4;
#pragma unroll
    for (int k = 0; k < 4; ++k) {
        int l = l0 + k;
        int node = (b << BSHIFT) + l;
        int st = 0;
#pragma unroll
        for (int c = 0; c < CHUNKS; ++c) {
            h[k][c] = histc[((size_t)hslot(b, c) << 10) + l];
            st += h[k][c];
        }
        stg[k] = st;
        int ov = (node < N) ? cnt_ovf[node] : 0;
        tv[k] = st + ov;
        run += tv[k];
    }
    part[tid] = run;
    __syncthreads();
    for (int off = 1; off < 256; off <<= 1) {
        int add = (tid >= off) ? part[tid - off] : 0;
        __syncthreads();
        part[tid] += add;
        __syncthreads();
    }
    int excl = part[tid] - run;
#pragma unroll
    for (int k = 0; k < 4; ++k) {
        int l = l0 + k;
        int node = (b << BSHIFT) + l;
        if (node < N) {
            roff[node] = base + excl;
            cursor[node] = base + excl + stg[k];     // overflow appended after staged
            dis[node] = rsqrtf((float)(tv[k] + 1));  // deg includes self-loop
        }
        int cb = base + excl;
#pragma unroll
        for (int c = 0; c < CHUNKS; ++c) {           // in-place: hist -> chunk base
            int hh = h[k][c];
            histc[((size_t)hslot(b, c) << 10) + l] = cb;
            cb += hh;
        }
        excl += tv[k];
    }
}

// --- phase C: per-sub-region scatter into CSR; 4 independent chains/thread.
//     Overflow sweep folded in (grid-stride; n==0 in practice). ---
__global__ __launch_bounds__(256) void k_scat2(const unsigned* __restrict__ pairs,
                                               const int* __restrict__ bcur8,
                                               const int* __restrict__ histc,
                                               int* __restrict__ csr,
                                               const unsigned long long* __restrict__ ovf,
                                               const int* __restrict__ ovfcnt,
                                               int* __restrict__ cursor, int nbuk) {
    __shared__ int cbase[BNODES];
    __shared__ int lc[BNODES];
    const int idx = blockIdx.x;
    const int c = (idx >> 3) & 7;
    const int b = (idx & 7) | ((idx >> 6) << 3);
    const int tid = threadIdx.x;
    if (b < nbuk) {
        const int nbc = min(bcur8[b * 8 + c], CAPS);
        const int i0 = c * CAPS, i1 = i0 + nbc;
        const unsigned* pp = pairs + (size_t)b * CAP;
        const int* hc = histc + ((size_t)idx << 10);
        for (int i = tid; i < BNODES; i += 256) { cbase[i] = hc[i]; lc[i] = 0; }
        __syncthreads();
        int i = i0 + tid;
        for (; i + 768 < i1; i += 1024) {
            unsigned e0 = pp[i], e1 = pp[i + 256], e2 = pp[i + 512], e3 = pp[i + 768];
            int l0 = e0 >> 17, l1 = e1 >> 17, l2 = e2 >> 17, l3 = e3 >> 17;
            int p0 = cbase[l0] + atomicAdd(&lc[l0], 1);
            int p1 = cbase[l1] + atomicAdd(&lc[l1], 1);
            int p2 = cbase[l2] + atomicAdd(&lc[l2], 1);
            int p3 = cbase[l3] + atomicAdd(&lc[l3], 1);
            csr[p0] = (int)(e0 & 0x1FFFFu);
            csr[p1] = (int)(e1 & 0x1FFFFu);
            csr[p2] = (int)(e2 & 0x1FFFFu);
            csr[p3] = (int)(e3 & 0x1FFFFu);
        }
        for (; i < i1; i += 256) {
            unsigned ent = pp[i];
            int l = ent >> 17;
            int pos = cbase[l] + atomicAdd(&lc[l], 1);
            csr[pos] = (int)(ent & 0x1FFFFu);
        }
    }
    // overflow sweep (disjoint csr positions via cursor; n==0 normally)
    int n = *ovfcnt;
    for (int i = idx * 256 + tid; i < n; i += gridDim.x * 256) {
        unsigned long long pr = ovf[i];
        int pos = atomicAdd(&cursor[(int)(unsigned)(pr >> 32)], 1);
        csr[pos] = (int)(unsigned)pr;
    }
}

// --- GEMM1: h1b[r] = bf16(dis[r] * (x[r] @ W1)) ---
__global__ __launch_bounds__(256) void k_gemm1(const float* __restrict__ x,
                                               const float* __restrict__ W,
                                               const float* __restrict__ dis,
                                               unsigned* __restrict__ h1b, int N) {
    __shared__ float sW[NF * HID];
    __shared__ float sx[32][132];
    const int t = threadIdx.x;
    for (int i = t; i < NF * HID; i += 256) sW[i] = W[i];
    const int row0 = blockIdx.x * 32;
    {
        const float4* xv = (const float4*)(x + (size_t)row0 * NF);
        for (int i = t; i < 32 * 32; i += 256) {
            int r = i >> 5, c = i & 31;
            float4 v = make_float4(0.f, 0.f, 0.f, 0.f);
            if (row0 + r < N) v = xv[(size_t)r * 32 + c];
            *(float4*)&sx[r][c * 4] = v;
        }
    }
    __syncthreads();
    const int col4 = (t & 7) * 4;
    const int row = t >> 3;
    float a0 = 0.f, a1 = 0.f, a2 = 0.f, a3 = 0.f;
#pragma unroll 8
    for (int k = 0; k < NF; ++k) {
        float xs = sx[row][k];
        float4 w = *(const float4*)&sW[k * HID + col4];
        a0 += xs * w.x; a1 += xs * w.y; a2 += xs * w.z; a3 += xs * w.w;
    }
    int r = row0 + row;
    if (r < N) {
        float d = dis[r];
        unsigned u0 = bf16rne(a0 * d) | (bf16rne(a1 * d) << 16);
        unsigned u1 = bf16rne(a2 * d) | (bf16rne(a3 * d) << 16);
        *(uint2*)&h1b[(size_t)r * 16 + (t & 7) * 2] = make_uint2(u0, u1);
    }
}

// --- agg1: t = bf16(dis * relu(dis*(self+sum) + b1)); unroll-8 gather ---
__global__ __launch_bounds__(256) void k_agg1(const uint4* __restrict__ h1b,
                                              const int* __restrict__ roff,
                                              const int* __restrict__ csr,
                                              const float* __restrict__ dis,
                                              const float* __restrict__ b1,
                                              uint4* __restrict__ t_out, int N) {
    int tt = blockIdx.x * 256 + threadIdx.x;
    int node = tt >> 2;
    if (node >= N) return;
    int j = tt & 3;
    uint4 u = h1b[(size_t)node * 4 + j];        // self-loop
    float a0, a1, a2, a3, a4, a5, a6, a7;
    a0 = __uint_as_float(u.x << 16); a1 = __uint_as_float(u.x & 0xffff0000u);
    a2 = __uint_as_float(u.y << 16); a3 = __uint_as_float(u.y & 0xffff0000u);
    a4 = __uint_as_float(u.z << 16); a5 = __uint_as_float(u.z & 0xffff0000u);
    a6 = __uint_as_float(u.w << 16); a7 = __uint_as_float(u.w & 0xffff0000u);
    int e0 = roff[node], e1 = roff[node + 1];
    int e = e0;
    for (; e + 8 <= e1; e += 8) {
        int s0 = __builtin_nontemporal_load(&csr[e + 0]);
        int s1 = __builtin_nontemporal_load(&csr[e + 1]);
        int s2 = __builtin_nontemporal_load(&csr[e + 2]);
        int s3 = __builtin_nontemporal_load(&csr[e + 3]);
        int s4 = __builtin_nontemporal_load(&csr[e + 4]);
        int s5 = __builtin_nontemporal_load(&csr[e + 5]);
        int s6 = __builtin_nontemporal_load(&csr[e + 6]);
        int s7 = __builtin_nontemporal_load(&csr[e + 7]);
        uint4 v0 = h1b[(size_t)s0 * 4 + j];
        uint4 v1 = h1b[(size_t)s1 * 4 + j];
        uint4 v2 = h1b[(size_t)s2 * 4 + j];
        uint4 v3 = h1b[(size_t)s3 * 4 + j];
        uint4 v4 = h1b[(size_t)s4 * 4 + j];
        uint4 v5 = h1b[(size_t)s5 * 4 + j];
        uint4 v6 = h1b[(size_t)s6 * 4 + j];
        uint4 v7 = h1b[(size_t)s7 * 4 + j];
        ACC8(v0) ACC8(v1) ACC8(v2) ACC8(v3) ACC8(v4) ACC8(v5) ACC8(v6) ACC8(v7)
    }
    for (; e + 4 <= e1; e += 4) {
        int s0 = __builtin_nontemporal_load(&csr[e + 0]);
        int s1 = __builtin_nontemporal_load(&csr[e + 1]);
        int s2 = __builtin_nontemporal_load(&csr[e + 2]);
        int s3 = __builtin_nontemporal_load(&csr[e + 3]);
        uint4 v0 = h1b[(size_t)s0 * 4 + j];
        uint4 v1 = h1b[(size_t)s1 * 4 + j];
        uint4 v2 = h1b[(size_t)s2 * 4 + j];
        uint4 v3 = h1b[(size_t)s3 * 4 + j];
        ACC8(v0) ACC8(v1) ACC8(v2) ACC8(v3)
    }
    for (; e < e1; ++e) {
        int s = __builtin_nontemporal_load(&csr[e]);
        uint4 v = h1b[(size_t)s * 4 + j];
        ACC8(v)
    }
    float d = dis[node];
    float4 bb0 = *(const float4*)&b1[j * 8];
    float4 bb1 = *(const float4*)&b1[j * 8 + 4];
    float r0 = fmaxf(a0 * d + bb0.x, 0.f) * d, r1 = fmaxf(a1 * d + bb0.y, 0.f) * d;
    float r2 = fmaxf(a2 * d + bb0.z, 0.f) * d, r3 = fmaxf(a3 * d + bb0.w, 0.f) * d;
    float r4 = fmaxf(a4 * d + bb1.x, 0.f) * d, r5 = fmaxf(a5 * d + bb1.y, 0.f) * d;
    float r6 = fmaxf(a6 * d + bb1.z, 0.f) * d, r7 = fmaxf(a7 * d + bb1.w, 0.f) * d;
    uint4 o;
    o.x = bf16rne(r0) | (bf16rne(r1) << 16);
    o.y = bf16rne(r2) | (bf16rne(r3) << 16);
    o.z = bf16rne(r4) | (bf16rne(r5) << 16);
    o.w = bf16rne(r6) | (bf16rne(r7) << 16);
    t_out[(size_t)node * 4 + j] = o;
}

// --- agg2: s2 = dis*(self + sum t[src]); fp32 out; unroll-8 gather ---
__global__ __launch_bounds__(256) void k_agg2(const uint4* __restrict__ tb,
                                              const int* __restrict__ roff,
                                              const int* __restrict__ csr,
                                              const float* __restrict__ dis,
                                              float* __restrict__ s2, int N) {
    int tt = blockIdx.x * 256 + threadIdx.x;
    int node = tt >> 2;
    if (node >= N) return;
    int j = tt & 3;
    uint4 u = tb[(size_t)node * 4 + j];         // self-loop
    float a0, a1, a2, a3, a4, a5, a6, a7;
    a0 = __uint_as_float(u.x << 16); a1 = __uint_as_float(u.x & 0xffff0000u);
    a2 = __uint_as_float(u.y << 16); a3 = __uint_as_float(u.y & 0xffff0000u);
    a4 = __uint_as_float(u.z << 16); a5 = __uint_as_float(u.z & 0xffff0000u);
    a6 = __uint_as_float(u.w << 16); a7 = __uint_as_float(u.w & 0xffff0000u);
    int e0 = roff[node], e1 = roff[node + 1];
    int e = e0;
    for (; e + 8 <= e1; e += 8) {
        int s0 = __builtin_nontemporal_load(&csr[e + 0]);
        int s1 = __builtin_nontemporal_load(&csr[e + 1]);
        int s2i = __builtin_nontemporal_load(&csr[e + 2]);
        int s3 = __builtin_nontemporal_load(&csr[e + 3]);
        int s4 = __builtin_nontemporal_load(&csr[e + 4]);
        int s5 = __builtin_nontemporal_load(&csr[e + 5]);
        int s6 = __builtin_nontemporal_load(&csr[e + 6]);
        int s7 = __builtin_nontemporal_load(&csr[e + 7]);
        uint4 v0 = tb[(size_t)s0 * 4 + j];
        uint4 v1 = tb[(size_t)s1 * 4 + j];
        uint4 v2 = tb[(size_t)s2i * 4 + j];
        uint4 v3 = tb[(size_t)s3 * 4 + j];
        uint4 v4 = tb[(size_t)s4 * 4 + j];
        uint4 v5 = tb[(size_t)s5 * 4 + j];
        uint4 v6 = tb[(size_t)s6 * 4 + j];
        uint4 v7 = tb[(size_t)s7 * 4 + j];
        ACC8(v0) ACC8(v1) ACC8(v2) ACC8(v3) ACC8(v4) ACC8(v5) ACC8(v6) ACC8(v7)
    }
    for (; e + 4 <= e1; e += 4) {
        int s0 = __builtin_nontemporal_load(&csr[e + 0]);
        int s1 = __builtin_nontemporal_load(&csr[e + 1]);
        int s2i = __builtin_nontemporal_load(&csr[e + 2]);
        int s3 = __builtin_nontemporal_load(&csr[e + 3]);
        uint4 v0 = tb[(size_t)s0 * 4 + j];
        uint4 v1 = tb[(size_t)s1 * 4 + j];
        uint4 v2 = tb[(size_t)s2i * 4 + j];
        uint4 v3 = tb[(size_t)s3 * 4 + j];
        ACC8(v0) ACC8(v1) ACC8(v2) ACC8(v3)
    }
    for (; e < e1; ++e) {
        int s = __builtin_nontemporal_load(&csr[e]);
        uint4 v = tb[(size_t)s * 4 + j];
        ACC8(v)
    }
    float d = dis[node];
    vf4 o0, o1;
    o0.x = a0 * d; o0.y = a1 * d; o0.z = a2 * d; o0.w = a3 * d;
    o1.x = a4 * d; o1.y = a5 * d; o1.z = a6 * d; o1.w = a7 * d;
    vf4* op = (vf4*)&s2[(size_t)node * HID + j * 8];
    __builtin_nontemporal_store(o0, op);
    __builtin_nontemporal_store(o1, op + 1);
}

// --- GEMM2: out[r] = s2[r] @ W2 + b2 ---
__global__ __launch_bounds__(256) void k_gemm2(const float* __restrict__ a,
                                               const float* __restrict__ W,
                                               const float* __restrict__ b2,
                                               float* __restrict__ out, int N) {
    __shared__ float sW[HID * EMB];
    __shared__ float sx[32][36];
    const int t = threadIdx.x;
    for (int i = t; i < HID * EMB; i += 256) sW[i] = W[i];
    const int row0 = blockIdx.x * 32;
    {
        const float4* av = (const float4*)(a + (size_t)row0 * HID);
        int r = t >> 3, c = t & 7;
        float4 v = make_float4(0.f, 0.f, 0.f, 0.f);
        if (row0 + r < N) v = av[(size_t)r * 8 + c];
        *(float4*)&sx[r][c * 4] = v;
    }
    __syncthreads();
    const int col4 = (t & 15) * 4;
    const int r0 = t >> 4;
    float a00 = 0.f, a01 = 0.f, a02 = 0.f, a03 = 0.f;
    float a10 = 0.f, a11 = 0.f, a12 = 0.f, a13 = 0.f;
#pragma unroll
    for (int k = 0; k < HID; ++k) {
        float4 w = *(const float4*)&sW[k * EMB + col4];
        float xa = sx[r0][k];
        float xb = sx[r0 + 16][k];
        a00 += xa * w.x; a01 += xa * w.y; a02 += xa * w.z; a03 += xa * w.w;
        a10 += xb * w.x; a11 += xb * w.y; a12 += xb * w.z; a13 += xb * w.w;
    }
    float4 bb = *(const float4*)&b2[col4];
    int ra = row0 + r0, rb = row0 + r0 + 16;
    if (ra < N) {
        vf4 o; o.x = a00 + bb.x; o.y = a01 + bb.y; o.z = a02 + bb.z; o.w = a03 + bb.w;
        __builtin_nontemporal_store(o, (vf4*)&out[(size_t)ra * EMB + col4]);
    }
    if (rb < N) {
        vf4 o; o.x = a10 + bb.x; o.y = a11 + bb.y; o.z = a12 + bb.z; o.w = a13 + bb.w;
        __builtin_nontemporal_store(o, (vf4*)&out[(size_t)rb * EMB + col4]);
    }
}

extern "C" void kernel_launch(void* const* d_in, const int* in_sizes, int n_in,
                              void* d_out, int out_size, void* d_ws, size_t ws_size,
                              hipStream_t stream) {
    const float* x  = (const float*)d_in[0];
    const void*  ei = d_in[1];
    const float* W1 = (const float*)d_in[2];
    const float* b1 = (const float*)d_in[3];
    const float* W2 = (const float*)d_in[4];
    const float* b2 = (const float*)d_in[5];
    float* out = (float*)d_out;

    const int N = in_sizes[0] / NF;              // 100000
    const int E = in_sizes[1] / 2;               // 3200000
    const int nbuk = (N + BNODES - 1) >> BSHIFT; // 98

    char* ws = (char*)d_ws;
    size_t off = 0;
    auto take = [&](size_t bytes) -> void* {
        void* p = ws + off;
        off += (bytes + 255) & ~(size_t)255;
        return p;
    };
    // zeroed region first (single memset)
    int* cnt_ovf = (int*)take((size_t)N * 4);
    int* bcur8   = (int*)take((size_t)NBUKMAX * 8 * 4);
    int* ovfcnt  = (int*)take(4);
    size_t zbytes = off;
    // rest
    int*                bbase  = (int*)take((size_t)NBUKMAX * 4);
    int*                roff   = (int*)take((size_t)(N + 1) * 4);
    int*                cursor = (int*)take((size_t)N * 4);
    float*              dis    = (float*)take((size_t)N * 4);
    int*                histc  = (int*)take((size_t)NBUKMAX * CHUNKS * BNODES * 4);
    unsigned*           pairs  = (unsigned*)take((size_t)nbuk * CAP * 4);
    unsigned long long* ovf    = (unsigned long long*)take((size_t)E * 8);
    int*                csr    = (int*)take((size_t)E * 4);
    unsigned*           h1b    = (unsigned*)take((size_t)N * HID * 2);
    unsigned*           tb     = (unsigned*)take((size_t)N * HID * 2);
    float*              s2     = (float*)take((size_t)N * HID * 4);

    (void)hipMemsetAsync(cnt_ovf, 0, zbytes, stream);

    const int gridBC = ((nbuk + 7) / 8) * 64;
    const int gridAgg = (int)(((size_t)N * 4 + 255) / 256);

    k_part<<<(E + TILE - 1) / TILE, 256, 0, stream>>>(ei, pairs, bcur8, cnt_ovf,
                                                      ovf, ovfcnt, E, nbuk);
    k_bscan<<<1, 128, 0, stream>>>(bcur8, bbase, roff, nbuk, E, N);
    k_hist<<<gridBC, 256, 0, stream>>>(pairs, bcur8, histc, nbuk);
    k_nscan<<<nbuk, 256, 0, stream>>>(histc, bbase, cnt_ovf, roff, cursor, dis, N);
    k_scat2<<<gridBC, 256, 0, stream>>>(pairs, bcur8, histc, csr, ovf, ovfcnt,
                                        cursor, nbuk);

    k_gemm1<<<(N + 31) / 32, 256, 0, stream>>>(x, W1, dis, h1b, N);
    k_agg1<<<gridAgg, 256, 0, stream>>>((const uint4*)h1b, roff, csr, dis, b1,
                                        (uint4*)tb, N);
    k_agg2<<<gridAgg, 256, 0, stream>>>((const uint4*)tb, roff, csr, dis, s2, N);
    k_gemm2<<<(N + 31) / 32, 256, 0, stream>>>(s2, W2, b2, out, N);
}

// Round 12
// 221.585 us; speedup vs baseline: 1.3152x; 1.0452x over previous
//
#include <hip/hip_runtime.h>
#include <hip/hip_bf16.h>

// ---------------------------------------------------------------------------
// 2-layer GCN (PyG GCNConv) N=100000, E=3.2M.
// Bucket-sort edges by dst (98 x 1024-node buckets, u32 entries), 3-phase
// parallel CSR build (TILE 4096, 8 per-bucket sub-regions keyed by
// blockIdx%8), then pull-based aggregation with algebraic reorder:
//   h1b = bf16(dis*(x@W1));  t = bf16(dis*relu(dis*agg(h1b)+b1))
//   out = (dis*agg(t)) @ W2 + b2   [gemm2 FUSED into agg2 epilogue]
// ---------------------------------------------------------------------------

#define NF 128
#define HID 32
#define EMB 64

#define BSHIFT 10
#define BNODES 1024
#define CAPS 4608                          // per-sub-region cap (mean 4082 + 8 sigma)
#define CAP (8 * CAPS)                     // 36864 per bucket
#define NBUKMAX 128
#define TILE 4096
#define EPT 16
#define CHUNKS 8

typedef float vf4 __attribute__((ext_vector_type(4)));
typedef unsigned vu4 __attribute__((ext_vector_type(4)));

static __device__ __forceinline__ unsigned bf16rne(float f) {
    unsigned u = __float_as_uint(f);
    return (u + 0x7fffu + ((u >> 16) & 1u)) >> 16;
}

// swizzled slot id: all CHUNKS chunks of bucket b share idx%8 == b%8
static __device__ __host__ __forceinline__ int hslot(int b, int c) {
    return ((b >> 3) << 6) | (c << 3) | (b & 7);
}

#define ACC8(v) \
    a0 += __uint_as_float((v).x << 16); a1 += __uint_as_float((v).x & 0xffff0000u); \
    a2 += __uint_as_float((v).y << 16); a3 += __uint_as_float((v).y & 0xffff0000u); \
    a4 += __uint_as_float((v).z << 16); a5 += __uint_as_float((v).z & 0xffff0000u); \
    a6 += __uint_as_float((v).w << 16); a7 += __uint_as_float((v).w & 0xffff0000u);

// --- multisplit into 1024-node dst-buckets; dtype detect fused; per-wave hist;
//     per-(bucket, blockIdx%8) sub-region reservation ---
__global__ __launch_bounds__(256) void k_part(const void* __restrict__ ei,
                                              unsigned* __restrict__ pairs,
                                              int* __restrict__ bcur8,
                                              int* __restrict__ cnt_ovf,
                                              unsigned long long* __restrict__ ovf,
                                              int* __restrict__ ovfcnt,
                                              int E, int nbuk) {
    __shared__ unsigned sEnt[TILE];            // 16 KB
    __shared__ unsigned char sB[TILE];         // 4 KB
    __shared__ int hcntw[4][NBUKMAX];          // per-wave hist -> per-wave cursor
    __shared__ int lstart[NBUKMAX], gbase[NBUKMAX];
    __shared__ int sNZ;
    const int tid = threadIdx.x;
    const int w = tid >> 6;
    const int grp = blockIdx.x & 7;            // sub-region key
    const int tile0 = blockIdx.x * TILE;
    if (tile0 >= E) return;
    const int tcnt = min(TILE, E - tile0);

    if (tid == 0) sNZ = 0;
    for (int b = tid; b < 4 * NBUKMAX; b += 256) ((int*)hcntw)[b] = 0;
    __syncthreads();
    {   // dtype detect on this tile: high words all zero <=> int64
        int i = tile0 + tid;
        if (i < E) {
            unsigned hw = ((const unsigned*)ei)[2 * (size_t)i + 1];
            if (hw) sNZ = 1;   // benign race
        }
    }
    __syncthreads();
    const bool is64 = (sNZ == 0);

    int ms[EPT], md[EPT];
#pragma unroll
    for (int k = 0; k < EPT; ++k) {
        int i = tile0 + k * 256 + tid;
        ms[k] = -1;
        if (i < tile0 + tcnt) {
            int s, d;
            if (is64) {
                const long long* p = (const long long*)ei;
                s = (int)__builtin_nontemporal_load(&p[i]);
                d = (int)__builtin_nontemporal_load(&p[(size_t)E + i]);
            } else {
                const int* p = (const int*)ei;
                s = __builtin_nontemporal_load(&p[i]);
                d = __builtin_nontemporal_load(&p[E + i]);
            }
            ms[k] = s; md[k] = d;
            atomicAdd(&hcntw[w][d >> BSHIFT], 1);
        }
    }
    __syncthreads();

    if (tid < 64) {  // wave 0: sum waves, scan buckets, reserve, per-wave bases
        int i0 = tid * 2, i1 = tid * 2 + 1;
        int c0 = 0, c1 = 0;
        if (i0 < nbuk) { c0 = hcntw[0][i0] + hcntw[1][i0] + hcntw[2][i0] + hcntw[3][i0]; }
        if (i1 < nbuk) { c1 = hcntw[0][i1] + hcntw[1][i1] + hcntw[2][i1] + hcntw[3][i1]; }
        int run = c0 + c1, inc = run;
#pragma unroll
        for (int off = 1; off < 64; off <<= 1) {
            int t2 = __shfl_up(inc, off);
            if (tid >= off) inc += t2;
        }
        int excl = inc - run;
        if (i0 < nbuk) {
            lstart[i0] = excl;
            gbase[i0] = c0 ? atomicAdd(&bcur8[i0 * 8 + grp], c0) : 0;
            int off2 = excl;
#pragma unroll
            for (int ww = 0; ww < 4; ++ww) { int t3 = hcntw[ww][i0]; hcntw[ww][i0] = off2; off2 += t3; }
        }
        if (i1 < nbuk) {
            lstart[i1] = excl + c0;
            gbase[i1] = c1 ? atomicAdd(&bcur8[i1 * 8 + grp], c1) : 0;
            int off2 = excl + c0;
#pragma unroll
            for (int ww = 0; ww < 4; ++ww) { int t3 = hcntw[ww][i1]; hcntw[ww][i1] = off2; off2 += t3; }
        }
    }
    __syncthreads();

#pragma unroll
    for (int k = 0; k < EPT; ++k) {
        if (ms[k] >= 0) {
            int b = md[k] >> BSHIFT;
            int slot = atomicAdd(&hcntw[w][b], 1);     // cursor = base (post-scan)
            sEnt[slot] = ((unsigned)(md[k] & (BNODES - 1)) << 17) | (unsigned)ms[k];
            sB[slot] = (unsigned char)b;
        }
    }
    __syncthreads();

    for (int j = tid; j < tcnt; j += 256) {   // bucket-ordered flush
        unsigned ent = sEnt[j];
        int b = sB[j];
        int g = gbase[b] + (j - lstart[b]);
        if (g < CAPS) {
            pairs[(size_t)b * CAP + grp * CAPS + g] = ent;
        } else {
            int d = (b << BSHIFT) | (int)(ent >> 17);
            int s = (int)(ent & 0x1FFFFu);
            int o = atomicAdd(ovfcnt, 1);
            ovf[o] = ((unsigned long long)(unsigned)d << 32) | (unsigned)s;
            atomicAdd(&cnt_ovf[d], 1);
        }
    }
}

// --- exclusive scan of bucket totals (sum of 8 sub-counters) -> CSR bases ---
__global__ void k_bscan(const int* __restrict__ bcur8, int* __restrict__ bbase,
                        int* __restrict__ roff, int nbuk, int E, int N) {
    __shared__ int sh[128];
    int t = threadIdx.x;  // blockDim=128, nbuk<=128
    int v = 0;
    if (t < nbuk) {
#pragma unroll
        for (int k = 0; k < 8; ++k) v += bcur8[t * 8 + k];   // true totals (incl ovf)
    }
    sh[t] = v;
    __syncthreads();
    for (int off = 1; off < 128; off <<= 1) {
        int add = (t >= off) ? sh[t - off] : 0;
        __syncthreads();
        sh[t] += add;
        __syncthreads();
    }
    if (t < nbuk) bbase[t] = sh[t] - v;
    if (t == 0) roff[N] = E;
}

// --- phase A: per-sub-region LDS histogram -> histc[slot][1024] ---
__global__ __launch_bounds__(256) void k_hist(const unsigned* __restrict__ pairs,
                                              const int* __restrict__ bcur8,
                                              int* __restrict__ histc, int nbuk) {
    __shared__ int hist[BNODES];
    const int idx = blockIdx.x;
    const int c = (idx >> 3) & 7;
    const int b = (idx & 7) | ((idx >> 6) << 3);
    if (b >= nbuk) return;
    const int tid = threadIdx.x;
    const int nbc = min(bcur8[b * 8 + c], CAPS);     // staged count in sub-region c
    const int i0 = c * CAPS, i1 = i0 + nbc;
    const unsigned* pp = pairs + (size_t)b * CAP;
    for (int i = tid; i < BNODES; i += 256) hist[i] = 0;
    __syncthreads();
    for (int i = i0 + tid; i < i1; i += 256)
        atomicAdd(&hist[__builtin_nontemporal_load(&pp[i]) >> 17], 1);
    __syncthreads();
    int* outp = histc + ((size_t)idx << 10);
    for (int i = tid; i < BNODES; i += 256) outp[i] = hist[i];
}

// --- phase B: per-bucket node scan -> roff/cursor/dis + chunk bases in histc ---
__global__ __launch_bounds__(256) void k_nscan(int* __restrict__ histc,
                                               const int* __restrict__ bbase,
                                               const int* __restrict__ cnt_ovf,
                                               int* __restrict__ roff,
                                               int* __restrict__ cursor,
                                               float* __restrict__ dis, int N) {
    __shared__ int part[256];
    const int b = blockIdx.x, tid = threadIdx.x;
    const int base = bbase[b];
    int h[4][CHUNKS], stg[4], tv[4];
    int run = 0;
    const int l0 = tid * 4;
#pragma unroll
    for (int k = 0; k < 4; ++k) {
        int l = l0 + k;
        int node = (b << BSHIFT) + l;
        int st = 0;
#pragma unroll
        for (int c = 0; c < CHUNKS; ++c) {
            h[k][c] = histc[((size_t)hslot(b, c) << 10) + l];
            st += h[k][c];
        }
        stg[k] = st;
        int ov = (node < N) ? cnt_ovf[node] : 0;
        tv[k] = st + ov;
        run += tv[k];
    }
    part[tid] = run;
    __syncthreads();
    for (int off = 1; off < 256; off <<= 1) {
        int add = (tid >= off) ? part[tid - off] : 0;
        __syncthreads();
        part[tid] += add;
        __syncthreads();
    }
    int excl = part[tid] - run;
#pragma unroll
    for (int k = 0; k < 4; ++k) {
        int l = l0 + k;
        int node = (b << BSHIFT) + l;
        if (node < N) {
            roff[node] = base + excl;
            cursor[node] = base + excl + stg[k];     // overflow appended after staged
            dis[node] = rsqrtf((float)(tv[k] + 1));  // deg includes self-loop
        }
        int cb = base + excl;
#pragma unroll
        for (int c = 0; c < CHUNKS; ++c) {           // in-place: hist -> chunk base
            int hh = h[k][c];
            histc[((size_t)hslot(b, c) << 10) + l] = cb;
            cb += hh;
        }
        excl += tv[k];
    }
}

// --- phase C: per-sub-region scatter into CSR; 4 independent chains/thread.
//     Overflow sweep folded in (grid-stride; n==0 in practice). ---
__global__ __launch_bounds__(256) void k_scat2(const unsigned* __restrict__ pairs,
                                               const int* __restrict__ bcur8,
                                               const int* __restrict__ histc,
                                               int* __restrict__ csr,
                                               const unsigned long long* __restrict__ ovf,
                                               const int* __restrict__ ovfcnt,
                                               int* __restrict__ cursor, int nbuk) {
    __shared__ int cbase[BNODES];
    __shared__ int lc[BNODES];
    const int idx = blockIdx.x;
    const int c = (idx >> 3) & 7;
    const int b = (idx & 7) | ((idx >> 6) << 3);
    const int tid = threadIdx.x;
    if (b < nbuk) {
        const int nbc = min(bcur8[b * 8 + c], CAPS);
        const int i0 = c * CAPS, i1 = i0 + nbc;
        const unsigned* pp = pairs + (size_t)b * CAP;
        const int* hc = histc + ((size_t)idx << 10);
        for (int i = tid; i < BNODES; i += 256) { cbase[i] = hc[i]; lc[i] = 0; }
        __syncthreads();
        int i = i0 + tid;
        for (; i + 768 < i1; i += 1024) {
            unsigned e0 = pp[i], e1 = pp[i + 256], e2 = pp[i + 512], e3 = pp[i + 768];
            int l0 = e0 >> 17, l1 = e1 >> 17, l2 = e2 >> 17, l3 = e3 >> 17;
            int p0 = cbase[l0] + atomicAdd(&lc[l0], 1);
            int p1 = cbase[l1] + atomicAdd(&lc[l1], 1);
            int p2 = cbase[l2] + atomicAdd(&lc[l2], 1);
            int p3 = cbase[l3] + atomicAdd(&lc[l3], 1);
            csr[p0] = (int)(e0 & 0x1FFFFu);
            csr[p1] = (int)(e1 & 0x1FFFFu);
            csr[p2] = (int)(e2 & 0x1FFFFu);
            csr[p3] = (int)(e3 & 0x1FFFFu);
        }
        for (; i < i1; i += 256) {
            unsigned ent = pp[i];
            int l = ent >> 17;
            int pos = cbase[l] + atomicAdd(&lc[l], 1);
            csr[pos] = (int)(ent & 0x1FFFFu);
        }
    }
    // overflow sweep (disjoint csr positions via cursor; n==0 normally)
    int n = *ovfcnt;
    for (int i = idx * 256 + tid; i < n; i += gridDim.x * 256) {
        unsigned long long pr = ovf[i];
        int pos = atomicAdd(&cursor[(int)(unsigned)(pr >> 32)], 1);
        csr[pos] = (int)(unsigned)pr;
    }
}

// --- GEMM1: h1b[r] = bf16(dis[r] * (x[r] @ W1)) ---
__global__ __launch_bounds__(256) void k_gemm1(const float* __restrict__ x,
                                               const float* __restrict__ W,
                                               const float* __restrict__ dis,
                                               unsigned* __restrict__ h1b, int N) {
    __shared__ float sW[NF * HID];
    __shared__ float sx[32][132];
    const int t = threadIdx.x;
    for (int i = t; i < NF * HID; i += 256) sW[i] = W[i];
    const int row0 = blockIdx.x * 32;
    {
        const float4* xv = (const float4*)(x + (size_t)row0 * NF);
        for (int i = t; i < 32 * 32; i += 256) {
            int r = i >> 5, c = i & 31;
            float4 v = make_float4(0.f, 0.f, 0.f, 0.f);
            if (row0 + r < N) v = xv[(size_t)r * 32 + c];
            *(float4*)&sx[r][c * 4] = v;
        }
    }
    __syncthreads();
    const int col4 = (t & 7) * 4;
    const int row = t >> 3;
    float a0 = 0.f, a1 = 0.f, a2 = 0.f, a3 = 0.f;
#pragma unroll 8
    for (int k = 0; k < NF; ++k) {
        float xs = sx[row][k];
        float4 w = *(const float4*)&sW[k * HID + col4];
        a0 += xs * w.x; a1 += xs * w.y; a2 += xs * w.z; a3 += xs * w.w;
    }
    int r = row0 + row;
    if (r < N) {
        float d = dis[r];
        unsigned u0 = bf16rne(a0 * d) | (bf16rne(a1 * d) << 16);
        unsigned u1 = bf16rne(a2 * d) | (bf16rne(a3 * d) << 16);
        *(uint2*)&h1b[(size_t)r * 16 + (t & 7) * 2] = make_uint2(u0, u1);
    }
}

// --- agg1: t = bf16(dis * relu(dis*(self+sum) + b1)); unroll-8 gather ---
__global__ __launch_bounds__(256) void k_agg1(const uint4* __restrict__ h1b,
                                              const int* __restrict__ roff,
                                              const int* __restrict__ csr,
                                              const float* __restrict__ dis,
                                              const float* __restrict__ b1,
                                              uint4* __restrict__ t_out, int N) {
    int tt = blockIdx.x * 256 + threadIdx.x;
    int node = tt >> 2;
    if (node >= N) return;
    int j = tt & 3;
    uint4 u = h1b[(size_t)node * 4 + j];        // self-loop
    float a0, a1, a2, a3, a4, a5, a6, a7;
    a0 = __uint_as_float(u.x << 16); a1 = __uint_as_float(u.x & 0xffff0000u);
    a2 = __uint_as_float(u.y << 16); a3 = __uint_as_float(u.y & 0xffff0000u);
    a4 = __uint_as_float(u.z << 16); a5 = __uint_as_float(u.z & 0xffff0000u);
    a6 = __uint_as_float(u.w << 16); a7 = __uint_as_float(u.w & 0xffff0000u);
    int e0 = roff[node], e1 = roff[node + 1];
    int e = e0;
    for (; e + 8 <= e1; e += 8) {
        int s0 = __builtin_nontemporal_load(&csr[e + 0]);
        int s1 = __builtin_nontemporal_load(&csr[e + 1]);
        int s2 = __builtin_nontemporal_load(&csr[e + 2]);
        int s3 = __builtin_nontemporal_load(&csr[e + 3]);
        int s4 = __builtin_nontemporal_load(&csr[e + 4]);
        int s5 = __builtin_nontemporal_load(&csr[e + 5]);
        int s6 = __builtin_nontemporal_load(&csr[e + 6]);
        int s7 = __builtin_nontemporal_load(&csr[e + 7]);
        uint4 v0 = h1b[(size_t)s0 * 4 + j];
        uint4 v1 = h1b[(size_t)s1 * 4 + j];
        uint4 v2 = h1b[(size_t)s2 * 4 + j];
        uint4 v3 = h1b[(size_t)s3 * 4 + j];
        uint4 v4 = h1b[(size_t)s4 * 4 + j];
        uint4 v5 = h1b[(size_t)s5 * 4 + j];
        uint4 v6 = h1b[(size_t)s6 * 4 + j];
        uint4 v7 = h1b[(size_t)s7 * 4 + j];
        ACC8(v0) ACC8(v1) ACC8(v2) ACC8(v3) ACC8(v4) ACC8(v5) ACC8(v6) ACC8(v7)
    }
    for (; e + 4 <= e1; e += 4) {
        int s0 = __builtin_nontemporal_load(&csr[e + 0]);
        int s1 = __builtin_nontemporal_load(&csr[e + 1]);
        int s2 = __builtin_nontemporal_load(&csr[e + 2]);
        int s3 = __builtin_nontemporal_load(&csr[e + 3]);
        uint4 v0 = h1b[(size_t)s0 * 4 + j];
        uint4 v1 = h1b[(size_t)s1 * 4 + j];
        uint4 v2 = h1b[(size_t)s2 * 4 + j];
        uint4 v3 = h1b[(size_t)s3 * 4 + j];
        ACC8(v0) ACC8(v1) ACC8(v2) ACC8(v3)
    }
    for (; e < e1; ++e) {
        int s = __builtin_nontemporal_load(&csr[e]);
        uint4 v = h1b[(size_t)s * 4 + j];
        ACC8(v)
    }
    float d = dis[node];
    float4 bb0 = *(const float4*)&b1[j * 8];
    float4 bb1 = *(const float4*)&b1[j * 8 + 4];
    float r0 = fmaxf(a0 * d + bb0.x, 0.f) * d, r1 = fmaxf(a1 * d + bb0.y, 0.f) * d;
    float r2 = fmaxf(a2 * d + bb0.z, 0.f) * d, r3 = fmaxf(a3 * d + bb0.w, 0.f) * d;
    float r4 = fmaxf(a4 * d + bb1.x, 0.f) * d, r5 = fmaxf(a5 * d + bb1.y, 0.f) * d;
    float r6 = fmaxf(a6 * d + bb1.z, 0.f) * d, r7 = fmaxf(a7 * d + bb1.w, 0.f) * d;
    uint4 o;
    o.x = bf16rne(r0) | (bf16rne(r1) << 16);
    o.y = bf16rne(r2) | (bf16rne(r3) << 16);
    o.z = bf16rne(r4) | (bf16rne(r5) << 16);
    o.w = bf16rne(r6) | (bf16rne(r7) << 16);
    t_out[(size_t)node * 4 + j] = o;
}

// --- agg2 + gemm2 FUSED: s2 = dis*(self + sum t[src]) staged in LDS,
//     then out[node] = s2 @ W2 + b2 (each lane computes 16 out channels) ---
__global__ __launch_bounds__(256) void k_agg2f(const uint4* __restrict__ tb,
                                               const int* __restrict__ roff,
                                               const int* __restrict__ csr,
                                               const float* __restrict__ dis,
                                               const float* __restrict__ W2,
                                               const float* __restrict__ b2,
                                               float* __restrict__ out, int N) {
    __shared__ float sW[HID * EMB];   // 8 KB
    __shared__ float sS[64][33];      // 8.25 KB, padded stride (bank-clean)
    const int tid = threadIdx.x;
    for (int i = tid; i < HID * EMB; i += 256) sW[i] = W2[i];
    int tt = blockIdx.x * 256 + tid;
    int node = tt >> 2;
    int j = tt & 3;
    int nl = tid >> 2;                // node-local row 0..63
    bool valid = (node < N);
    if (valid) {
        uint4 u = tb[(size_t)node * 4 + j];     // self-loop
        float a0, a1, a2, a3, a4, a5, a6, a7;
        a0 = __uint_as_float(u.x << 16); a1 = __uint_as_float(u.x & 0xffff0000u);
        a2 = __uint_as_float(u.y << 16); a3 = __uint_as_float(u.y & 0xffff0000u);
        a4 = __uint_as_float(u.z << 16); a5 = __uint_as_float(u.z & 0xffff0000u);
        a6 = __uint_as_float(u.w << 16); a7 = __uint_as_float(u.w & 0xffff0000u);
        int e0 = roff[node], e1 = roff[node + 1];
        int e = e0;
        for (; e + 8 <= e1; e += 8) {
            int s0 = __builtin_nontemporal_load(&csr[e + 0]);
            int s1 = __builtin_nontemporal_load(&csr[e + 1]);
            int s2i = __builtin_nontemporal_load(&csr[e + 2]);
            int s3 = __builtin_nontemporal_load(&csr[e + 3]);
            int s4 = __builtin_nontemporal_load(&csr[e + 4]);
            int s5 = __builtin_nontemporal_load(&csr[e + 5]);
            int s6 = __builtin_nontemporal_load(&csr[e + 6]);
            int s7 = __builtin_nontemporal_load(&csr[e + 7]);
            uint4 v0 = tb[(size_t)s0 * 4 + j];
            uint4 v1 = tb[(size_t)s1 * 4 + j];
            uint4 v2 = tb[(size_t)s2i * 4 + j];
            uint4 v3 = tb[(size_t)s3 * 4 + j];
            uint4 v4 = tb[(size_t)s4 * 4 + j];
            uint4 v5 = tb[(size_t)s5 * 4 + j];
            uint4 v6 = tb[(size_t)s6 * 4 + j];
            uint4 v7 = tb[(size_t)s7 * 4 + j];
            ACC8(v0) ACC8(v1) ACC8(v2) ACC8(v3) ACC8(v4) ACC8(v5) ACC8(v6) ACC8(v7)
        }
        for (; e + 4 <= e1; e += 4) {
            int s0 = __builtin_nontemporal_load(&csr[e + 0]);
            int s1 = __builtin_nontemporal_load(&csr[e + 1]);
            int s2i = __builtin_nontemporal_load(&csr[e + 2]);
            int s3 = __builtin_nontemporal_load(&csr[e + 3]);
            uint4 v0 = tb[(size_t)s0 * 4 + j];
            uint4 v1 = tb[(size_t)s1 * 4 + j];
            uint4 v2 = tb[(size_t)s2i * 4 + j];
            uint4 v3 = tb[(size_t)s3 * 4 + j];
            ACC8(v0) ACC8(v1) ACC8(v2) ACC8(v3)
        }
        for (; e < e1; ++e) {
            int s = __builtin_nontemporal_load(&csr[e]);
            uint4 v = tb[(size_t)s * 4 + j];
            ACC8(v)
        }
        float d = dis[node];
        float* sp = &sS[nl][j * 8];
        sp[0] = a0 * d; sp[1] = a1 * d; sp[2] = a2 * d; sp[3] = a3 * d;
        sp[4] = a4 * d; sp[5] = a5 * d; sp[6] = a6 * d; sp[7] = a7 * d;
    }
    __syncthreads();
    if (valid) {
        const int cb = j * 16;   // this lane's 16 output channels
        float4 c0 = *(const float4*)&b2[cb];
        float4 c1 = *(const float4*)&b2[cb + 4];
        float4 c2 = *(const float4*)&b2[cb + 8];
        float4 c3 = *(const float4*)&b2[cb + 12];
#pragma unroll 8
        for (int k = 0; k < HID; ++k) {
            float s = sS[nl][k];
            const float4* w = (const float4*)&sW[k * EMB + cb];
            float4 w0 = w[0], w1 = w[1], w2 = w[2], w3 = w[3];
            c0.x += s * w0.x; c0.y += s * w0.y; c0.z += s * w0.z; c0.w += s * w0.w;
            c1.x += s * w1.x; c1.y += s * w1.y; c1.z += s * w1.z; c1.w += s * w1.w;
            c2.x += s * w2.x; c2.y += s * w2.y; c2.z += s * w2.z; c2.w += s * w2.w;
            c3.x += s * w3.x; c3.y += s * w3.y; c3.z += s * w3.z; c3.w += s * w3.w;
        }
        float* op = &out[(size_t)node * EMB + cb];
        vf4 o0, o1, o2, o3;
        o0.x = c0.x; o0.y = c0.y; o0.z = c0.z; o0.w = c0.w;
        o1.x = c1.x; o1.y = c1.y; o1.z = c1.z; o1.w = c1.w;
        o2.x = c2.x; o2.y = c2.y; o2.z = c2.z; o2.w = c2.w;
        o3.x = c3.x; o3.y = c3.y; o3.z = c3.z; o3.w = c3.w;
        __builtin_nontemporal_store(o0, (vf4*)op);
        __builtin_nontemporal_store(o1, (vf4*)(op + 4));
        __builtin_nontemporal_store(o2, (vf4*)(op + 8));
        __builtin_nontemporal_store(o3, (vf4*)(op + 12));
    }
}

extern "C" void kernel_launch(void* const* d_in, const int* in_sizes, int n_in,
                              void* d_out, int out_size, void* d_ws, size_t ws_size,
                              hipStream_t stream) {
    const float* x  = (const float*)d_in[0];
    const void*  ei = d_in[1];
    const float* W1 = (const float*)d_in[2];
    const float* b1 = (const float*)d_in[3];
    const float* W2 = (const float*)d_in[4];
    const float* b2 = (const float*)d_in[5];
    float* out = (float*)d_out;

    const int N = in_sizes[0] / NF;              // 100000
    const int E = in_sizes[1] / 2;               // 3200000
    const int nbuk = (N + BNODES - 1) >> BSHIFT; // 98

    char* ws = (char*)d_ws;
    size_t off = 0;
    auto take = [&](size_t bytes) -> void* {
        void* p = ws + off;
        off += (bytes + 255) & ~(size_t)255;
        return p;
    };
    // zeroed region first (single memset)
    int* cnt_ovf = (int*)take((size_t)N * 4);
    int* bcur8   = (int*)take((size_t)NBUKMAX * 8 * 4);
    int* ovfcnt  = (int*)take(4);
    size_t zbytes = off;
    // rest
    int*                bbase  = (int*)take((size_t)NBUKMAX * 4);
    int*                roff   = (int*)take((size_t)(N + 1) * 4);
    int*                cursor = (int*)take((size_t)N * 4);
    float*              dis    = (float*)take((size_t)N * 4);
    int*                histc  = (int*)take((size_t)NBUKMAX * CHUNKS * BNODES * 4);
    unsigned*           pairs  = (unsigned*)take((size_t)nbuk * CAP * 4);
    unsigned long long* ovf    = (unsigned long long*)take((size_t)E * 8);
    int*                csr    = (int*)take((size_t)E * 4);
    unsigned*           h1b    = (unsigned*)take((size_t)N * HID * 2);
    unsigned*           tb     = (unsigned*)take((size_t)N * HID * 2);

    (void)hipMemsetAsync(cnt_ovf, 0, zbytes, stream);

    const int gridBC = ((nbuk + 7) / 8) * 64;
    const int gridAgg = (int)(((size_t)N * 4 + 255) / 256);

    k_part<<<(E + TILE - 1) / TILE, 256, 0, stream>>>(ei, pairs, bcur8, cnt_ovf,
                                                      ovf, ovfcnt, E, nbuk);
    k_bscan<<<1, 128, 0, stream>>>(bcur8, bbase, roff, nbuk, E, N);
    k_hist<<<gridBC, 256, 0, stream>>>(pairs, bcur8, histc, nbuk);
    k_nscan<<<nbuk, 256, 0, stream>>>(histc, bbase, cnt_ovf, roff, cursor, dis, N);
    k_scat2<<<gridBC, 256, 0, stream>>>(pairs, bcur8, histc, csr, ovf, ovfcnt,
                                        cursor, nbuk);

    k_gemm1<<<(N + 31) / 32, 256, 0, stream>>>(x, W1, dis, h1b, N);
    k_agg1<<<gridAgg, 256, 0, stream>>>((const uint4*)h1b, roff, csr, dis, b1,
                                        (uint4*)tb, N);
    k_agg2f<<<gridAgg, 256, 0, stream>>>((const uint4*)tb, roff, csr, dis,
                                         W2, b2, out, N);
}

// Round 13
// 213.186 us; speedup vs baseline: 1.3670x; 1.0394x over previous
//
#include <hip/hip_runtime.h>
#include <hip/hip_bf16.h>

// ---------------------------------------------------------------------------
// 2-layer GCN (PyG GCNConv) N=100000, E=3.2M.
// Bucket-sort edges by dst (98 x 1024-node buckets, u32 entries), 3-phase
// parallel CSR build (TILE 4096, 8 per-bucket sub-regions keyed by
// blockIdx%8; 512-thread blocks for latency hiding), then pull-based
// aggregation with algebraic reorder:
//   h1b = bf16(dis*(x@W1));  t = bf16(dis*relu(dis*agg(h1b)+b1))
//   out = (dis*agg(t)) @ W2 + b2   [gemm2 fused into agg2 epilogue]
// ---------------------------------------------------------------------------

#define NF 128
#define HID 32
#define EMB 64

#define BSHIFT 10
#define BNODES 1024
#define CAPS 4608                          // per-sub-region cap (mean 4082 + 8 sigma)
#define CAP (8 * CAPS)                     // 36864 per bucket
#define NBUKMAX 128
#define TILE 4096
#define EPT 8                              // 512 threads x 8 = TILE
#define CHUNKS 8

typedef float vf4 __attribute__((ext_vector_type(4)));
typedef unsigned vu4 __attribute__((ext_vector_type(4)));

static __device__ __forceinline__ unsigned bf16rne(float f) {
    unsigned u = __float_as_uint(f);
    return (u + 0x7fffu + ((u >> 16) & 1u)) >> 16;
}

// swizzled slot id: all CHUNKS chunks of bucket b share idx%8 == b%8
static __device__ __host__ __forceinline__ int hslot(int b, int c) {
    return ((b >> 3) << 6) | (c << 3) | (b & 7);
}

#define ACC8(v) \
    a0 += __uint_as_float((v).x << 16); a1 += __uint_as_float((v).x & 0xffff0000u); \
    a2 += __uint_as_float((v).y << 16); a3 += __uint_as_float((v).y & 0xffff0000u); \
    a4 += __uint_as_float((v).z << 16); a5 += __uint_as_float((v).z & 0xffff0000u); \
    a6 += __uint_as_float((v).w << 16); a7 += __uint_as_float((v).w & 0xffff0000u);

// --- multisplit into 1024-node dst-buckets; dtype detect fused; per-wave hist;
//     per-(bucket, blockIdx%8) sub-region reservation. 512 threads (8 waves). ---
__global__ __launch_bounds__(512) void k_part(const void* __restrict__ ei,
                                              unsigned* __restrict__ pairs,
                                              int* __restrict__ bcur8,
                                              int* __restrict__ cnt_ovf,
                                              unsigned long long* __restrict__ ovf,
                                              int* __restrict__ ovfcnt,
                                              int E, int nbuk) {
    __shared__ unsigned sEnt[TILE];            // 16 KB
    __shared__ unsigned char sB[TILE];         // 4 KB
    __shared__ int hcntw[8][NBUKMAX];          // per-wave hist -> per-wave cursor
    __shared__ int lstart[NBUKMAX], gbase[NBUKMAX];
    __shared__ int sNZ;
    const int tid = threadIdx.x;
    const int w = tid >> 6;
    const int grp = blockIdx.x & 7;            // sub-region key
    const int tile0 = blockIdx.x * TILE;
    if (tile0 >= E) return;
    const int tcnt = min(TILE, E - tile0);

    if (tid == 0) sNZ = 0;
    for (int b = tid; b < 8 * NBUKMAX; b += 512) ((int*)hcntw)[b] = 0;
    __syncthreads();
    {   // dtype detect on this tile: high words all zero <=> int64
        int i = tile0 + tid;
        if (i < E) {
            unsigned hw = ((const unsigned*)ei)[2 * (size_t)i + 1];
            if (hw) sNZ = 1;   // benign race
        }
    }
    __syncthreads();
    const bool is64 = (sNZ == 0);

    int ms[EPT], md[EPT];
#pragma unroll
    for (int k = 0; k < EPT; ++k) {
        int i = tile0 + k * 512 + tid;
        ms[k] = -1;
        if (i < tile0 + tcnt) {
            int s, d;
            if (is64) {
                const long long* p = (const long long*)ei;
                s = (int)__builtin_nontemporal_load(&p[i]);
                d = (int)__builtin_nontemporal_load(&p[(size_t)E + i]);
            } else {
                const int* p = (const int*)ei;
                s = __builtin_nontemporal_load(&p[i]);
                d = __builtin_nontemporal_load(&p[E + i]);
            }
            ms[k] = s; md[k] = d;
            atomicAdd(&hcntw[w][d >> BSHIFT], 1);
        }
    }
    __syncthreads();

    if (tid < 64) {  // wave 0: sum waves, scan buckets, reserve, per-wave bases
        int i0 = tid * 2, i1 = tid * 2 + 1;
        int c0 = 0, c1 = 0;
        if (i0 < nbuk) {
#pragma unroll
            for (int ww = 0; ww < 8; ++ww) c0 += hcntw[ww][i0];
        }
        if (i1 < nbuk) {
#pragma unroll
            for (int ww = 0; ww < 8; ++ww) c1 += hcntw[ww][i1];
        }
        int run = c0 + c1, inc = run;
#pragma unroll
        for (int off = 1; off < 64; off <<= 1) {
            int t2 = __shfl_up(inc, off);
            if (tid >= off) inc += t2;
        }
        int excl = inc - run;
        if (i0 < nbuk) {
            lstart[i0] = excl;
            gbase[i0] = c0 ? atomicAdd(&bcur8[i0 * 8 + grp], c0) : 0;
            int off2 = excl;
#pragma unroll
            for (int ww = 0; ww < 8; ++ww) { int t3 = hcntw[ww][i0]; hcntw[ww][i0] = off2; off2 += t3; }
        }
        if (i1 < nbuk) {
            lstart[i1] = excl + c0;
            gbase[i1] = c1 ? atomicAdd(&bcur8[i1 * 8 + grp], c1) : 0;
            int off2 = excl + c0;
#pragma unroll
            for (int ww = 0; ww < 8; ++ww) { int t3 = hcntw[ww][i1]; hcntw[ww][i1] = off2; off2 += t3; }
        }
    }
    __syncthreads();

#pragma unroll
    for (int k = 0; k < EPT; ++k) {
        if (ms[k] >= 0) {
            int b = md[k] >> BSHIFT;
            int slot = atomicAdd(&hcntw[w][b], 1);     // cursor = base (post-scan)
            sEnt[slot] = ((unsigned)(md[k] & (BNODES - 1)) << 17) | (unsigned)ms[k];
            sB[slot] = (unsigned char)b;
        }
    }
    __syncthreads();

    for (int j = tid; j < tcnt; j += 512) {   // bucket-ordered flush
        unsigned ent = sEnt[j];
        int b = sB[j];
        int g = gbase[b] + (j - lstart[b]);
        if (g < CAPS) {
            pairs[(size_t)b * CAP + grp * CAPS + g] = ent;
        } else {
            int d = (b << BSHIFT) | (int)(ent >> 17);
            int s = (int)(ent & 0x1FFFFu);
            int o = atomicAdd(ovfcnt, 1);
            ovf[o] = ((unsigned long long)(unsigned)d << 32) | (unsigned)s;
            atomicAdd(&cnt_ovf[d], 1);
        }
    }
}

// --- exclusive scan of bucket totals (sum of 8 sub-counters) -> CSR bases ---
__global__ void k_bscan(const int* __restrict__ bcur8, int* __restrict__ bbase,
                        int* __restrict__ roff, int nbuk, int E, int N) {
    __shared__ int sh[128];
    int t = threadIdx.x;  // blockDim=128, nbuk<=128
    int v = 0;
    if (t < nbuk) {
#pragma unroll
        for (int k = 0; k < 8; ++k) v += bcur8[t * 8 + k];   // true totals (incl ovf)
    }
    sh[t] = v;
    __syncthreads();
    for (int off = 1; off < 128; off <<= 1) {
        int add = (t >= off) ? sh[t - off] : 0;
        __syncthreads();
        sh[t] += add;
        __syncthreads();
    }
    if (t < nbuk) bbase[t] = sh[t] - v;
    if (t == 0) roff[N] = E;
}

// --- phase A: per-sub-region LDS histogram -> histc[slot][1024]; 512 thr ---
__global__ __launch_bounds__(512) void k_hist(const unsigned* __restrict__ pairs,
                                              const int* __restrict__ bcur8,
                                              int* __restrict__ histc, int nbuk) {
    __shared__ int hist[BNODES];
    const int idx = blockIdx.x;
    const int c = (idx >> 3) & 7;
    const int b = (idx & 7) | ((idx >> 6) << 3);
    if (b >= nbuk) return;
    const int tid = threadIdx.x;
    const int nbc = min(bcur8[b * 8 + c], CAPS);     // staged count in sub-region c
    const int i0 = c * CAPS, i1 = i0 + nbc;
    const unsigned* pp = pairs + (size_t)b * CAP;
    for (int i = tid; i < BNODES; i += 512) hist[i] = 0;
    __syncthreads();
    for (int i = i0 + tid; i < i1; i += 512)
        atomicAdd(&hist[__builtin_nontemporal_load(&pp[i]) >> 17], 1);
    __syncthreads();
    int* outp = histc + ((size_t)idx << 10);
    for (int i = tid; i < BNODES; i += 512) outp[i] = hist[i];
}

// --- phase B: per-bucket node scan -> roff/cursor/dis + chunk bases in histc ---
__global__ __launch_bounds__(256) void k_nscan(int* __restrict__ histc,
                                               const int* __restrict__ bbase,
                                               const int* __restrict__ cnt_ovf,
                                               int* __restrict__ roff,
                                               int* __restrict__ cursor,
                                               float* __restrict__ dis, int N) {
    __shared__ int part[256];
    const int b = blockIdx.x, tid = threadIdx.x;
    const int base = bbase[b];
    int h[4][CHUNKS], stg[4], tv[4];
    int run = 0;
    const int l0 = tid * 4;
#pragma unroll
    for (int k = 0; k < 4; ++k) {
        int l = l0 + k;
        int node = (b << BSHIFT) + l;
        int st = 0;
#pragma unroll
        for (int c = 0; c < CHUNKS; ++c) {
            h[k][c] = histc[((size_t)hslot(b, c) << 10) + l];
            st += h[k][c];
        }
        stg[k] = st;
        int ov = (node < N) ? cnt_ovf[node] : 0;
        tv[k] = st + ov;
        run += tv[k];
    }
    part[tid] = run;
    __syncthreads();
    for (int off = 1; off < 256; off <<= 1) {
        int add = (tid >= off) ? part[tid - off] : 0;
        __syncthreads();
        part[tid] += add;
        __syncthreads();
    }
    int excl = part[tid] - run;
#pragma unroll
    for (int k = 0; k < 4; ++k) {
        int l = l0 + k;
        int node = (b << BSHIFT) + l;
        if (node < N) {
            roff[node] = base + excl;
            cursor[node] = base + excl + stg[k];     // overflow appended after staged
            dis[node] = rsqrtf((float)(tv[k] + 1));  // deg includes self-loop
        }
        int cb = base + excl;
#pragma unroll
        for (int c = 0; c < CHUNKS; ++c) {           // in-place: hist -> chunk base
            int hh = h[k][c];
            histc[((size_t)hslot(b, c) << 10) + l] = cb;
            cb += hh;
        }
        excl += tv[k];
    }
}

// --- phase C: per-sub-region scatter into CSR; 512 thr, 4 chains/thread.
//     Overflow sweep folded in (grid-stride; n==0 in practice). ---
__global__ __launch_bounds__(512) void k_scat2(const unsigned* __restrict__ pairs,
                                               const int* __restrict__ bcur8,
                                               const int* __restrict__ histc,
                                               int* __restrict__ csr,
                                               const unsigned long long* __restrict__ ovf,
                                               const int* __restrict__ ovfcnt,
                                               int* __restrict__ cursor, int nbuk) {
    __shared__ int cbase[BNODES];
    __shared__ int lc[BNODES];
    const int idx = blockIdx.x;
    const int c = (idx >> 3) & 7;
    const int b = (idx & 7) | ((idx >> 6) << 3);
    const int tid = threadIdx.x;
    if (b < nbuk) {
        const int nbc = min(bcur8[b * 8 + c], CAPS);
        const int i0 = c * CAPS, i1 = i0 + nbc;
        const unsigned* pp = pairs + (size_t)b * CAP;
        const int* hc = histc + ((size_t)idx << 10);
        for (int i = tid; i < BNODES; i += 512) { cbase[i] = hc[i]; lc[i] = 0; }
        __syncthreads();
        int i = i0 + tid;
        for (; i + 1536 < i1; i += 2048) {
            unsigned e0 = pp[i], e1 = pp[i + 512], e2 = pp[i + 1024], e3 = pp[i + 1536];
            int l0 = e0 >> 17, l1 = e1 >> 17, l2 = e2 >> 17, l3 = e3 >> 17;
            int p0 = cbase[l0] + atomicAdd(&lc[l0], 1);
            int p1 = cbase[l1] + atomicAdd(&lc[l1], 1);
            int p2 = cbase[l2] + atomicAdd(&lc[l2], 1);
            int p3 = cbase[l3] + atomicAdd(&lc[l3], 1);
            csr[p0] = (int)(e0 & 0x1FFFFu);
            csr[p1] = (int)(e1 & 0x1FFFFu);
            csr[p2] = (int)(e2 & 0x1FFFFu);
            csr[p3] = (int)(e3 & 0x1FFFFu);
        }
        for (; i < i1; i += 512) {
            unsigned ent = pp[i];
            int l = ent >> 17;
            int pos = cbase[l] + atomicAdd(&lc[l], 1);
            csr[pos] = (int)(ent & 0x1FFFFu);
        }
    }
    // overflow sweep (disjoint csr positions via cursor; n==0 normally)
    int n = *ovfcnt;
    for (int i = idx * 512 + tid; i < n; i += gridDim.x * 512) {
        unsigned long long pr = ovf[i];
        int pos = atomicAdd(&cursor[(int)(unsigned)(pr >> 32)], 1);
        csr[pos] = (int)(unsigned)pr;
    }
}

// --- GEMM1: h1b[r] = bf16(dis[r] * (x[r] @ W1)) ---
__global__ __launch_bounds__(256) void k_gemm1(const float* __restrict__ x,
                                               const float* __restrict__ W,
                                               const float* __restrict__ dis,
                                               unsigned* __restrict__ h1b, int N) {
    __shared__ float sW[NF * HID];
    __shared__ float sx[32][132];
    const int t = threadIdx.x;
    for (int i = t; i < NF * HID; i += 256) sW[i] = W[i];
    const int row0 = blockIdx.x * 32;
    {
        const float4* xv = (const float4*)(x + (size_t)row0 * NF);
        for (int i = t; i < 32 * 32; i += 256) {
            int r = i >> 5, c = i & 31;
            float4 v = make_float4(0.f, 0.f, 0.f, 0.f);
            if (row0 + r < N) v = xv[(size_t)r * 32 + c];
            *(float4*)&sx[r][c * 4] = v;
        }
    }
    __syncthreads();
    const int col4 = (t & 7) * 4;
    const int row = t >> 3;
    float a0 = 0.f, a1 = 0.f, a2 = 0.f, a3 = 0.f;
#pragma unroll 8
    for (int k = 0; k < NF; ++k) {
        float xs = sx[row][k];
        float4 w = *(const float4*)&sW[k * HID + col4];
        a0 += xs * w.x; a1 += xs * w.y; a2 += xs * w.z; a3 += xs * w.w;
    }
    int r = row0 + row;
    if (r < N) {
        float d = dis[r];
        unsigned u0 = bf16rne(a0 * d) | (bf16rne(a1 * d) << 16);
        unsigned u1 = bf16rne(a2 * d) | (bf16rne(a3 * d) << 16);
        *(uint2*)&h1b[(size_t)r * 16 + (t & 7) * 2] = make_uint2(u0, u1);
    }
}

// --- agg1: t = bf16(dis * relu(dis*(self+sum) + b1)); unroll-8 gather ---
__global__ __launch_bounds__(256) void k_agg1(const uint4* __restrict__ h1b,
                                              const int* __restrict__ roff,
                                              const int* __restrict__ csr,
                                              const float* __restrict__ dis,
                                              const float* __restrict__ b1,
                                              uint4* __restrict__ t_out, int N) {
    int tt = blockIdx.x * 256 + threadIdx.x;
    int node = tt >> 2;
    if (node >= N) return;
    int j = tt & 3;
    uint4 u = h1b[(size_t)node * 4 + j];        // self-loop
    float a0, a1, a2, a3, a4, a5, a6, a7;
    a0 = __uint_as_float(u.x << 16); a1 = __uint_as_float(u.x & 0xffff0000u);
    a2 = __uint_as_float(u.y << 16); a3 = __uint_as_float(u.y & 0xffff0000u);
    a4 = __uint_as_float(u.z << 16); a5 = __uint_as_float(u.z & 0xffff0000u);
    a6 = __uint_as_float(u.w << 16); a7 = __uint_as_float(u.w & 0xffff0000u);
    int e0 = roff[node], e1 = roff[node + 1];
    int e = e0;
    for (; e + 8 <= e1; e += 8) {
        int s0 = __builtin_nontemporal_load(&csr[e + 0]);
        int s1 = __builtin_nontemporal_load(&csr[e + 1]);
        int s2 = __builtin_nontemporal_load(&csr[e + 2]);
        int s3 = __builtin_nontemporal_load(&csr[e + 3]);
        int s4 = __builtin_nontemporal_load(&csr[e + 4]);
        int s5 = __builtin_nontemporal_load(&csr[e + 5]);
        int s6 = __builtin_nontemporal_load(&csr[e + 6]);
        int s7 = __builtin_nontemporal_load(&csr[e + 7]);
        uint4 v0 = h1b[(size_t)s0 * 4 + j];
        uint4 v1 = h1b[(size_t)s1 * 4 + j];
        uint4 v2 = h1b[(size_t)s2 * 4 + j];
        uint4 v3 = h1b[(size_t)s3 * 4 + j];
        uint4 v4 = h1b[(size_t)s4 * 4 + j];
        uint4 v5 = h1b[(size_t)s5 * 4 + j];
        uint4 v6 = h1b[(size_t)s6 * 4 + j];
        uint4 v7 = h1b[(size_t)s7 * 4 + j];
        ACC8(v0) ACC8(v1) ACC8(v2) ACC8(v3) ACC8(v4) ACC8(v5) ACC8(v6) ACC8(v7)
    }
    for (; e + 4 <= e1; e += 4) {
        int s0 = __builtin_nontemporal_load(&csr[e + 0]);
        int s1 = __builtin_nontemporal_load(&csr[e + 1]);
        int s2 = __builtin_nontemporal_load(&csr[e + 2]);
        int s3 = __builtin_nontemporal_load(&csr[e + 3]);
        uint4 v0 = h1b[(size_t)s0 * 4 + j];
        uint4 v1 = h1b[(size_t)s1 * 4 + j];
        uint4 v2 = h1b[(size_t)s2 * 4 + j];
        uint4 v3 = h1b[(size_t)s3 * 4 + j];
        ACC8(v0) ACC8(v1) ACC8(v2) ACC8(v3)
    }
    for (; e < e1; ++e) {
        int s = __builtin_nontemporal_load(&csr[e]);
        uint4 v = h1b[(size_t)s * 4 + j];
        ACC8(v)
    }
    float d = dis[node];
    float4 bb0 = *(const float4*)&b1[j * 8];
    float4 bb1 = *(const float4*)&b1[j * 8 + 4];
    float r0 = fmaxf(a0 * d + bb0.x, 0.f) * d, r1 = fmaxf(a1 * d + bb0.y, 0.f) * d;
    float r2 = fmaxf(a2 * d + bb0.z, 0.f) * d, r3 = fmaxf(a3 * d + bb0.w, 0.f) * d;
    float r4 = fmaxf(a4 * d + bb1.x, 0.f) * d, r5 = fmaxf(a5 * d + bb1.y, 0.f) * d;
    float r6 = fmaxf(a6 * d + bb1.z, 0.f) * d, r7 = fmaxf(a7 * d + bb1.w, 0.f) * d;
    uint4 o;
    o.x = bf16rne(r0) | (bf16rne(r1) << 16);
    o.y = bf16rne(r2) | (bf16rne(r3) << 16);
    o.z = bf16rne(r4) | (bf16rne(r5) << 16);
    o.w = bf16rne(r6) | (bf16rne(r7) << 16);
    t_out[(size_t)node * 4 + j] = o;
}

// --- agg2 + gemm2 FUSED: s2 = dis*(self + sum t[src]) staged in LDS,
//     then out[node] = s2 @ W2 + b2 (each lane computes 16 out channels) ---
__global__ __launch_bounds__(256) void k_agg2f(const uint4* __restrict__ tb,
                                               const int* __restrict__ roff,
                                               const int* __restrict__ csr,
                                               const float* __restrict__ dis,
                                               const float* __restrict__ W2,
                                               const float* __restrict__ b2,
                                               float* __restrict__ out, int N) {
    __shared__ float sW[HID * EMB];   // 8 KB
    __shared__ float sS[64][33];      // 8.25 KB, padded stride (bank-clean)
    const int tid = threadIdx.x;
    for (int i = tid; i < HID * EMB; i += 256) sW[i] = W2[i];
    int tt = blockIdx.x * 256 + tid;
    int node = tt >> 2;
    int j = tt & 3;
    int nl = tid >> 2;                // node-local row 0..63
    bool valid = (node < N);
    if (valid) {
        uint4 u = tb[(size_t)node * 4 + j];     // self-loop
        float a0, a1, a2, a3, a4, a5, a6, a7;
        a0 = __uint_as_float(u.x << 16); a1 = __uint_as_float(u.x & 0xffff0000u);
        a2 = __uint_as_float(u.y << 16); a3 = __uint_as_float(u.y & 0xffff0000u);
        a4 = __uint_as_float(u.z << 16); a5 = __uint_as_float(u.z & 0xffff0000u);
        a6 = __uint_as_float(u.w << 16); a7 = __uint_as_float(u.w & 0xffff0000u);
        int e0 = roff[node], e1 = roff[node + 1];
        int e = e0;
        for (; e + 8 <= e1; e += 8) {
            int s0 = __builtin_nontemporal_load(&csr[e + 0]);
            int s1 = __builtin_nontemporal_load(&csr[e + 1]);
            int s2i = __builtin_nontemporal_load(&csr[e + 2]);
            int s3 = __builtin_nontemporal_load(&csr[e + 3]);
            int s4 = __builtin_nontemporal_load(&csr[e + 4]);
            int s5 = __builtin_nontemporal_load(&csr[e + 5]);
            int s6 = __builtin_nontemporal_load(&csr[e + 6]);
            int s7 = __builtin_nontemporal_load(&csr[e + 7]);
            uint4 v0 = tb[(size_t)s0 * 4 + j];
            uint4 v1 = tb[(size_t)s1 * 4 + j];
            uint4 v2 = tb[(size_t)s2i * 4 + j];
            uint4 v3 = tb[(size_t)s3 * 4 + j];
            uint4 v4 = tb[(size_t)s4 * 4 + j];
            uint4 v5 = tb[(size_t)s5 * 4 + j];
            uint4 v6 = tb[(size_t)s6 * 4 + j];
            uint4 v7 = tb[(size_t)s7 * 4 + j];
            ACC8(v0) ACC8(v1) ACC8(v2) ACC8(v3) ACC8(v4) ACC8(v5) ACC8(v6) ACC8(v7)
        }
        for (; e + 4 <= e1; e += 4) {
            int s0 = __builtin_nontemporal_load(&csr[e + 0]);
            int s1 = __builtin_nontemporal_load(&csr[e + 1]);
            int s2i = __builtin_nontemporal_load(&csr[e + 2]);
            int s3 = __builtin_nontemporal_load(&csr[e + 3]);
            uint4 v0 = tb[(size_t)s0 * 4 + j];
            uint4 v1 = tb[(size_t)s1 * 4 + j];
            uint4 v2 = tb[(size_t)s2i * 4 + j];
            uint4 v3 = tb[(size_t)s3 * 4 + j];
            ACC8(v0) ACC8(v1) ACC8(v2) ACC8(v3)
        }
        for (; e < e1; ++e) {
            int s = __builtin_nontemporal_load(&csr[e]);
            uint4 v = tb[(size_t)s * 4 + j];
            ACC8(v)
        }
        float d = dis[node];
        float* sp = &sS[nl][j * 8];
        sp[0] = a0 * d; sp[1] = a1 * d; sp[2] = a2 * d; sp[3] = a3 * d;
        sp[4] = a4 * d; sp[5] = a5 * d; sp[6] = a6 * d; sp[7] = a7 * d;
    }
    __syncthreads();
    if (valid) {
        const int cb = j * 16;   // this lane's 16 output channels
        float4 c0 = *(const float4*)&b2[cb];
        float4 c1 = *(const float4*)&b2[cb + 4];
        float4 c2 = *(const float4*)&b2[cb + 8];
        float4 c3 = *(const float4*)&b2[cb + 12];
#pragma unroll 8
        for (int k = 0; k < HID; ++k) {
            float s = sS[nl][k];
            const float4* w = (const float4*)&sW[k * EMB + cb];
            float4 w0 = w[0], w1 = w[1], w2 = w[2], w3 = w[3];
            c0.x += s * w0.x; c0.y += s * w0.y; c0.z += s * w0.z; c0.w += s * w0.w;
            c1.x += s * w1.x; c1.y += s * w1.y; c1.z += s * w1.z; c1.w += s * w1.w;
            c2.x += s * w2.x; c2.y += s * w2.y; c2.z += s * w2.z; c2.w += s * w2.w;
            c3.x += s * w3.x; c3.y += s * w3.y; c3.z += s * w3.z; c3.w += s * w3.w;
        }
        float* op = &out[(size_t)node * EMB + cb];
        vf4 o0, o1, o2, o3;
        o0.x = c0.x; o0.y = c0.y; o0.z = c0.z; o0.w = c0.w;
        o1.x = c1.x; o1.y = c1.y; o1.z = c1.z; o1.w = c1.w;
        o2.x = c2.x; o2.y = c2.y; o2.z = c2.z; o2.w = c2.w;
        o3.x = c3.x; o3.y = c3.y; o3.z = c3.z; o3.w = c3.w;
        __builtin_nontemporal_store(o0, (vf4*)op);
        __builtin_nontemporal_store(o1, (vf4*)(op + 4));
        __builtin_nontemporal_store(o2, (vf4*)(op + 8));
        __builtin_nontemporal_store(o3, (vf4*)(op + 12));
    }
}

extern "C" void kernel_launch(void* const* d_in, const int* in_sizes, int n_in,
                              void* d_out, int out_size, void* d_ws, size_t ws_size,
                              hipStream_t stream) {
    const float* x  = (const float*)d_in[0];
    const void*  ei = d_in[1];
    const float* W1 = (const float*)d_in[2];
    const float* b1 = (const float*)d_in[3];
    const float* W2 = (const float*)d_in[4];
    const float* b2 = (const float*)d_in[5];
    float* out = (float*)d_out;

    const int N = in_sizes[0] / NF;              // 100000
    const int E = in_sizes[1] / 2;               // 3200000
    const int nbuk = (N + BNODES - 1) >> BSHIFT; // 98

    char* ws = (char*)d_ws;
    size_t off = 0;
    auto take = [&](size_t bytes) -> void* {
        void* p = ws + off;
        off += (bytes + 255) & ~(size_t)255;
        return p;
    };
    // zeroed region first (single memset)
    int* cnt_ovf = (int*)take((size_t)N * 4);
    int* bcur8   = (int*)take((size_t)NBUKMAX * 8 * 4);
    int* ovfcnt  = (int*)take(4);
    size_t zbytes = off;
    // rest
    int*                bbase  = (int*)take((size_t)NBUKMAX * 4);
    int*                roff   = (int*)take((size_t)(N + 1) * 4);
    int*                cursor = (int*)take((size_t)N * 4);
    float*              dis    = (float*)take((size_t)N * 4);
    int*                histc  = (int*)take((size_t)NBUKMAX * CHUNKS * BNODES * 4);
    unsigned*           pairs  = (unsigned*)take((size_t)nbuk * CAP * 4);
    unsigned long long* ovf    = (unsigned long long*)take((size_t)E * 8);
    int*                csr    = (int*)take((size_t)E * 4);
    unsigned*           h1b    = (unsigned*)take((size_t)N * HID * 2);
    unsigned*           tb     = (unsigned*)take((size_t)N * HID * 2);

    (void)hipMemsetAsync(cnt_ovf, 0, zbytes, stream);

    const int gridBC = ((nbuk + 7) / 8) * 64;
    const int gridAgg = (int)(((size_t)N * 4 + 255) / 256);

    k_part<<<(E + TILE - 1) / TILE, 512, 0, stream>>>(ei, pairs, bcur8, cnt_ovf,
                                                      ovf, ovfcnt, E, nbuk);
    k_bscan<<<1, 128, 0, stream>>>(bcur8, bbase, roff, nbuk, E, N);
    k_hist<<<gridBC, 512, 0, stream>>>(pairs, bcur8, histc, nbuk);
    k_nscan<<<nbuk, 256, 0, stream>>>(histc, bbase, cnt_ovf, roff, cursor, dis, N);
    k_scat2<<<gridBC, 512, 0, stream>>>(pairs, bcur8, histc, csr, ovf, ovfcnt,
                                        cursor, nbuk);

    k_gemm1<<<(N + 31) / 32, 256, 0, stream>>>(x, W1, dis, h1b, N);
    k_agg1<<<gridAgg, 256, 0, stream>>>((const uint4*)h1b, roff, csr, dis, b1,
                                        (uint4*)tb, N);
    k_agg2f<<<gridAgg, 256, 0, stream>>>((const uint4*)tb, roff, csr, dis,
                                         W2, b2, out, N);
}

// Round 14
// 211.683 us; speedup vs baseline: 1.3767x; 1.0071x over previous
//
#include <hip/hip_runtime.h>
#include <hip/hip_bf16.h>

// ---------------------------------------------------------------------------
// 2-layer GCN (PyG GCNConv) N=100000, E=3.2M.
// Bucket-sort edges by dst (98 x 1024-node buckets, u32 entries), 3-phase
// parallel CSR build (TILE 4096, 8 per-bucket sub-regions keyed by
// blockIdx%8; 512-thread blocks), then pull-based aggregation with
// algebraic reorder:
//   h1b = bf16(dis*(x@W1));  t = bf16(dis*relu(dis*agg(h1b)+b1))
//   out = (dis*agg(t)) @ W2 + b2   [gemm2 fused into agg2 epilogue]
// Round 14: gather unroll 8 -> 16 in aggs (2x memory-level parallelism).
// ---------------------------------------------------------------------------

#define NF 128
#define HID 32
#define EMB 64

#define BSHIFT 10
#define BNODES 1024
#define CAPS 4608                          // per-sub-region cap (mean 4082 + 8 sigma)
#define CAP (8 * CAPS)                     // 36864 per bucket
#define NBUKMAX 128
#define TILE 4096
#define EPT 8                              // 512 threads x 8 = TILE
#define CHUNKS 8

typedef float vf4 __attribute__((ext_vector_type(4)));
typedef unsigned vu4 __attribute__((ext_vector_type(4)));

static __device__ __forceinline__ unsigned bf16rne(float f) {
    unsigned u = __float_as_uint(f);
    return (u + 0x7fffu + ((u >> 16) & 1u)) >> 16;
}

// swizzled slot id: all CHUNKS chunks of bucket b share idx%8 == b%8
static __device__ __host__ __forceinline__ int hslot(int b, int c) {
    return ((b >> 3) << 6) | (c << 3) | (b & 7);
}

#define ACC8(v) \
    a0 += __uint_as_float((v).x << 16); a1 += __uint_as_float((v).x & 0xffff0000u); \
    a2 += __uint_as_float((v).y << 16); a3 += __uint_as_float((v).y & 0xffff0000u); \
    a4 += __uint_as_float((v).z << 16); a5 += __uint_as_float((v).z & 0xffff0000u); \
    a6 += __uint_as_float((v).w << 16); a7 += __uint_as_float((v).w & 0xffff0000u);

// 16-deep gather+accumulate over one edge batch (rows are uint4-indexed, *4+j)
#define GATHER16(TBL) \
    { \
        int s0 = __builtin_nontemporal_load(&csr[e + 0]); \
        int s1 = __builtin_nontemporal_load(&csr[e + 1]); \
        int s2_ = __builtin_nontemporal_load(&csr[e + 2]); \
        int s3 = __builtin_nontemporal_load(&csr[e + 3]); \
        int s4 = __builtin_nontemporal_load(&csr[e + 4]); \
        int s5 = __builtin_nontemporal_load(&csr[e + 5]); \
        int s6 = __builtin_nontemporal_load(&csr[e + 6]); \
        int s7 = __builtin_nontemporal_load(&csr[e + 7]); \
        int s8 = __builtin_nontemporal_load(&csr[e + 8]); \
        int s9 = __builtin_nontemporal_load(&csr[e + 9]); \
        int sa = __builtin_nontemporal_load(&csr[e + 10]); \
        int sb = __builtin_nontemporal_load(&csr[e + 11]); \
        int sc = __builtin_nontemporal_load(&csr[e + 12]); \
        int sd = __builtin_nontemporal_load(&csr[e + 13]); \
        int se = __builtin_nontemporal_load(&csr[e + 14]); \
        int sf = __builtin_nontemporal_load(&csr[e + 15]); \
        uint4 v0 = TBL[(size_t)s0 * 4 + j]; \
        uint4 v1 = TBL[(size_t)s1 * 4 + j]; \
        uint4 v2 = TBL[(size_t)s2_ * 4 + j]; \
        uint4 v3 = TBL[(size_t)s3 * 4 + j]; \
        uint4 v4 = TBL[(size_t)s4 * 4 + j]; \
        uint4 v5 = TBL[(size_t)s5 * 4 + j]; \
        uint4 v6 = TBL[(size_t)s6 * 4 + j]; \
        uint4 v7 = TBL[(size_t)s7 * 4 + j]; \
        uint4 v8 = TBL[(size_t)s8 * 4 + j]; \
        uint4 v9 = TBL[(size_t)s9 * 4 + j]; \
        uint4 va = TBL[(size_t)sa * 4 + j]; \
        uint4 vb = TBL[(size_t)sb * 4 + j]; \
        uint4 vc = TBL[(size_t)sc * 4 + j]; \
        uint4 vd = TBL[(size_t)sd * 4 + j]; \
        uint4 ve = TBL[(size_t)se * 4 + j]; \
        uint4 vf = TBL[(size_t)sf * 4 + j]; \
        ACC8(v0) ACC8(v1) ACC8(v2) ACC8(v3) ACC8(v4) ACC8(v5) ACC8(v6) ACC8(v7) \
        ACC8(v8) ACC8(v9) ACC8(va) ACC8(vb) ACC8(vc) ACC8(vd) ACC8(ve) ACC8(vf) \
    }

#define GATHER4(TBL) \
    { \
        int s0 = __builtin_nontemporal_load(&csr[e + 0]); \
        int s1 = __builtin_nontemporal_load(&csr[e + 1]); \
        int s2_ = __builtin_nontemporal_load(&csr[e + 2]); \
        int s3 = __builtin_nontemporal_load(&csr[e + 3]); \
        uint4 v0 = TBL[(size_t)s0 * 4 + j]; \
        uint4 v1 = TBL[(size_t)s1 * 4 + j]; \
        uint4 v2 = TBL[(size_t)s2_ * 4 + j]; \
        uint4 v3 = TBL[(size_t)s3 * 4 + j]; \
        ACC8(v0) ACC8(v1) ACC8(v2) ACC8(v3) \
    }

// --- multisplit into 1024-node dst-buckets; dtype detect fused; per-wave hist;
//     per-(bucket, blockIdx%8) sub-region reservation. 512 threads (8 waves). ---
__global__ __launch_bounds__(512) void k_part(const void* __restrict__ ei,
                                              unsigned* __restrict__ pairs,
                                              int* __restrict__ bcur8,
                                              int* __restrict__ cnt_ovf,
                                              unsigned long long* __restrict__ ovf,
                                              int* __restrict__ ovfcnt,
                                              int E, int nbuk) {
    __shared__ unsigned sEnt[TILE];            // 16 KB
    __shared__ unsigned char sB[TILE];         // 4 KB
    __shared__ int hcntw[8][NBUKMAX];          // per-wave hist -> per-wave cursor
    __shared__ int lstart[NBUKMAX], gbase[NBUKMAX];
    __shared__ int sNZ;
    const int tid = threadIdx.x;
    const int w = tid >> 6;
    const int grp = blockIdx.x & 7;            // sub-region key
    const int tile0 = blockIdx.x * TILE;
    if (tile0 >= E) return;
    const int tcnt = min(TILE, E - tile0);

    if (tid == 0) sNZ = 0;
    for (int b = tid; b < 8 * NBUKMAX; b += 512) ((int*)hcntw)[b] = 0;
    __syncthreads();
    {   // dtype detect on this tile: high words all zero <=> int64
        int i = tile0 + tid;
        if (i < E) {
            unsigned hw = ((const unsigned*)ei)[2 * (size_t)i + 1];
            if (hw) sNZ = 1;   // benign race
        }
    }
    __syncthreads();
    const bool is64 = (sNZ == 0);

    int ms[EPT], md[EPT];
#pragma unroll
    for (int k = 0; k < EPT; ++k) {
        int i = tile0 + k * 512 + tid;
        ms[k] = -1;
        if (i < tile0 + tcnt) {
            int s, d;
            if (is64) {
                const long long* p = (const long long*)ei;
                s = (int)__builtin_nontemporal_load(&p[i]);
                d = (int)__builtin_nontemporal_load(&p[(size_t)E + i]);
            } else {
                const int* p = (const int*)ei;
                s = __builtin_nontemporal_load(&p[i]);
                d = __builtin_nontemporal_load(&p[E + i]);
            }
            ms[k] = s; md[k] = d;
            atomicAdd(&hcntw[w][d >> BSHIFT], 1);
        }
    }
    __syncthreads();

    if (tid < 64) {  // wave 0: sum waves, scan buckets, reserve, per-wave bases
        int i0 = tid * 2, i1 = tid * 2 + 1;
        int c0 = 0, c1 = 0;
        if (i0 < nbuk) {
#pragma unroll
            for (int ww = 0; ww < 8; ++ww) c0 += hcntw[ww][i0];
        }
        if (i1 < nbuk) {
#pragma unroll
            for (int ww = 0; ww < 8; ++ww) c1 += hcntw[ww][i1];
        }
        int run = c0 + c1, inc = run;
#pragma unroll
        for (int off = 1; off < 64; off <<= 1) {
            int t2 = __shfl_up(inc, off);
            if (tid >= off) inc += t2;
        }
        int excl = inc - run;
        if (i0 < nbuk) {
            lstart[i0] = excl;
            gbase[i0] = c0 ? atomicAdd(&bcur8[i0 * 8 + grp], c0) : 0;
            int off2 = excl;
#pragma unroll
            for (int ww = 0; ww < 8; ++ww) { int t3 = hcntw[ww][i0]; hcntw[ww][i0] = off2; off2 += t3; }
        }
        if (i1 < nbuk) {
            lstart[i1] = excl + c0;
            gbase[i1] = c1 ? atomicAdd(&bcur8[i1 * 8 + grp], c1) : 0;
            int off2 = excl + c0;
#pragma unroll
            for (int ww = 0; ww < 8; ++ww) { int t3 = hcntw[ww][i1]; hcntw[ww][i1] = off2; off2 += t3; }
        }
    }
    __syncthreads();

#pragma unroll
    for (int k = 0; k < EPT; ++k) {
        if (ms[k] >= 0) {
            int b = md[k] >> BSHIFT;
            int slot = atomicAdd(&hcntw[w][b], 1);     // cursor = base (post-scan)
            sEnt[slot] = ((unsigned)(md[k] & (BNODES - 1)) << 17) | (unsigned)ms[k];
            sB[slot] = (unsigned char)b;
        }
    }
    __syncthreads();

    for (int j = tid; j < tcnt; j += 512) {   // bucket-ordered flush
        unsigned ent = sEnt[j];
        int b = sB[j];
        int g = gbase[b] + (j - lstart[b]);
        if (g < CAPS) {
            pairs[(size_t)b * CAP + grp * CAPS + g] = ent;
        } else {
            int d = (b << BSHIFT) | (int)(ent >> 17);
            int s = (int)(ent & 0x1FFFFu);
            int o = atomicAdd(ovfcnt, 1);
            ovf[o] = ((unsigned long long)(unsigned)d << 32) | (unsigned)s;
            atomicAdd(&cnt_ovf[d], 1);
        }
    }
}

// --- exclusive scan of bucket totals (sum of 8 sub-counters) -> CSR bases ---
__global__ void k_bscan(const int* __restrict__ bcur8, int* __restrict__ bbase,
                        int* __restrict__ roff, int nbuk, int E, int N) {
    __shared__ int sh[128];
    int t = threadIdx.x;  // blockDim=128, nbuk<=128
    int v = 0;
    if (t < nbuk) {
#pragma unroll
        for (int k = 0; k < 8; ++k) v += bcur8[t * 8 + k];   // true totals (incl ovf)
    }
    sh[t] = v;
    __syncthreads();
    for (int off = 1; off < 128; off <<= 1) {
        int add = (t >= off) ? sh[t - off] : 0;
        __syncthreads();
        sh[t] += add;
        __syncthreads();
    }
    if (t < nbuk) bbase[t] = sh[t] - v;
    if (t == 0) roff[N] = E;
}

// --- phase A: per-sub-region LDS histogram -> histc[slot][1024]; 512 thr ---
__global__ __launch_bounds__(512) void k_hist(const unsigned* __restrict__ pairs,
                                              const int* __restrict__ bcur8,
                                              int* __restrict__ histc, int nbuk) {
    __shared__ int hist[BNODES];
    const int idx = blockIdx.x;
    const int c = (idx >> 3) & 7;
    const int b = (idx & 7) | ((idx >> 6) << 3);
    if (b >= nbuk) return;
    const int tid = threadIdx.x;
    const int nbc = min(bcur8[b * 8 + c], CAPS);     // staged count in sub-region c
    const int i0 = c * CAPS, i1 = i0 + nbc;
    const unsigned* pp = pairs + (size_t)b * CAP;
    for (int i = tid; i < BNODES; i += 512) hist[i] = 0;
    __syncthreads();
    for (int i = i0 + tid; i < i1; i += 512)
        atomicAdd(&hist[__builtin_nontemporal_load(&pp[i]) >> 17], 1);
    __syncthreads();
    int* outp = histc + ((size_t)idx << 10);
    for (int i = tid; i < BNODES; i += 512) outp[i] = hist[i];
}

// --- phase B: per-bucket node scan -> roff/cursor/dis + chunk bases in histc ---
__global__ __launch_bounds__(256) void k_nscan(int* __restrict__ histc,
                                               const int* __restrict__ bbase,
                                               const int* __restrict__ cnt_ovf,
                                               int* __restrict__ roff,
                                               int* __restrict__ cursor,
                                               float* __restrict__ dis, int N) {
    __shared__ int part[256];
    const int b = blockIdx.x, tid = threadIdx.x;
    const int base = bbase[b];
    int h[4][CHUNKS], stg[4], tv[4];
    int run = 0;
    const int l0 = tid * 4;
#pragma unroll
    for (int k = 0; k < 4; ++k) {
        int l = l0 + k;
        int node = (b << BSHIFT) + l;
        int st = 0;
#pragma unroll
        for (int c = 0; c < CHUNKS; ++c) {
            h[k][c] = histc[((size_t)hslot(b, c) << 10) + l];
            st += h[k][c];
        }
        stg[k] = st;
        int ov = (node < N) ? cnt_ovf[node] : 0;
        tv[k] = st + ov;
        run += tv[k];
    }
    part[tid] = run;
    __syncthreads();
    for (int off = 1; off < 256; off <<= 1) {
        int add = (tid >= off) ? part[tid - off] : 0;
        __syncthreads();
        part[tid] += add;
        __syncthreads();
    }
    int excl = part[tid] - run;
#pragma unroll
    for (int k = 0; k < 4; ++k) {
        int l = l0 + k;
        int node = (b << BSHIFT) + l;
        if (node < N) {
            roff[node] = base + excl;
            cursor[node] = base + excl + stg[k];     // overflow appended after staged
            dis[node] = rsqrtf((float)(tv[k] + 1));  // deg includes self-loop
        }
        int cb = base + excl;
#pragma unroll
        for (int c = 0; c < CHUNKS; ++c) {           // in-place: hist -> chunk base
            int hh = h[k][c];
            histc[((size_t)hslot(b, c) << 10) + l] = cb;
            cb += hh;
        }
        excl += tv[k];
    }
}

// --- phase C: per-sub-region scatter into CSR; 512 thr, 4 chains/thread.
//     Overflow sweep folded in (grid-stride; n==0 in practice). ---
__global__ __launch_bounds__(512) void k_scat2(const unsigned* __restrict__ pairs,
                                               const int* __restrict__ bcur8,
                                               const int* __restrict__ histc,
                                               int* __restrict__ csr,
                                               const unsigned long long* __restrict__ ovf,
                                               const int* __restrict__ ovfcnt,
                                               int* __restrict__ cursor, int nbuk) {
    __shared__ int cbase[BNODES];
    __shared__ int lc[BNODES];
    const int idx = blockIdx.x;
    const int c = (idx >> 3) & 7;
    const int b = (idx & 7) | ((idx >> 6) << 3);
    const int tid = threadIdx.x;
    if (b < nbuk) {
        const int nbc = min(bcur8[b * 8 + c], CAPS);
        const int i0 = c * CAPS, i1 = i0 + nbc;
        const unsigned* pp = pairs + (size_t)b * CAP;
        const int* hc = histc + ((size_t)idx << 10);
        for (int i = tid; i < BNODES; i += 512) { cbase[i] = hc[i]; lc[i] = 0; }
        __syncthreads();
        int i = i0 + tid;
        for (; i + 1536 < i1; i += 2048) {
            unsigned e0 = pp[i], e1 = pp[i + 512], e2 = pp[i + 1024], e3 = pp[i + 1536];
            int l0 = e0 >> 17, l1 = e1 >> 17, l2 = e2 >> 17, l3 = e3 >> 17;
            int p0 = cbase[l0] + atomicAdd(&lc[l0], 1);
            int p1 = cbase[l1] + atomicAdd(&lc[l1], 1);
            int p2 = cbase[l2] + atomicAdd(&lc[l2], 1);
            int p3 = cbase[l3] + atomicAdd(&lc[l3], 1);
            csr[p0] = (int)(e0 & 0x1FFFFu);
            csr[p1] = (int)(e1 & 0x1FFFFu);
            csr[p2] = (int)(e2 & 0x1FFFFu);
            csr[p3] = (int)(e3 & 0x1FFFFu);
        }
        for (; i < i1; i += 512) {
            unsigned ent = pp[i];
            int l = ent >> 17;
            int pos = cbase[l] + atomicAdd(&lc[l], 1);
            csr[pos] = (int)(ent & 0x1FFFFu);
        }
    }
    // overflow sweep (disjoint csr positions via cursor; n==0 normally)
    int n = *ovfcnt;
    for (int i = idx * 512 + tid; i < n; i += gridDim.x * 512) {
        unsigned long long pr = ovf[i];
        int pos = atomicAdd(&cursor[(int)(unsigned)(pr >> 32)], 1);
        csr[pos] = (int)(unsigned)pr;
    }
}

// --- GEMM1: h1b[r] = bf16(dis[r] * (x[r] @ W1)) ---
__global__ __launch_bounds__(256) void k_gemm1(const float* __restrict__ x,
                                               const float* __restrict__ W,
                                               const float* __restrict__ dis,
                                               unsigned* __restrict__ h1b, int N) {
    __shared__ float sW[NF * HID];
    __shared__ float sx[32][132];
    const int t = threadIdx.x;
    for (int i = t; i < NF * HID; i += 256) sW[i] = W[i];
    const int row0 = blockIdx.x * 32;
    {
        const float4* xv = (const float4*)(x + (size_t)row0 * NF);
        for (int i = t; i < 32 * 32; i += 256) {
            int r = i >> 5, c = i & 31;
            float4 v = make_float4(0.f, 0.f, 0.f, 0.f);
            if (row0 + r < N) v = xv[(size_t)r * 32 + c];
            *(float4*)&sx[r][c * 4] = v;
        }
    }
    __syncthreads();
    const int col4 = (t & 7) * 4;
    const int row = t >> 3;
    float a0 = 0.f, a1 = 0.f, a2 = 0.f, a3 = 0.f;
#pragma unroll 8
    for (int k = 0; k < NF; ++k) {
        float xs = sx[row][k];
        float4 w = *(const float4*)&sW[k * HID + col4];
        a0 += xs * w.x; a1 += xs * w.y; a2 += xs * w.z; a3 += xs * w.w;
    }
    int r = row0 + row;
    if (r < N) {
        float d = dis[r];
        unsigned u0 = bf16rne(a0 * d) | (bf16rne(a1 * d) << 16);
        unsigned u1 = bf16rne(a2 * d) | (bf16rne(a3 * d) << 16);
        *(uint2*)&h1b[(size_t)r * 16 + (t & 7) * 2] = make_uint2(u0, u1);
    }
}

// --- agg1: t = bf16(dis * relu(dis*(self+sum) + b1)); unroll-16 gather ---
__global__ __launch_bounds__(256) void k_agg1(const uint4* __restrict__ h1b,
                                              const int* __restrict__ roff,
                                              const int* __restrict__ csr,
                                              const float* __restrict__ dis,
                                              const float* __restrict__ b1,
                                              uint4* __restrict__ t_out, int N) {
    int tt = blockIdx.x * 256 + threadIdx.x;
    int node = tt >> 2;
    if (node >= N) return;
    int j = tt & 3;
    uint4 u = h1b[(size_t)node * 4 + j];        // self-loop
    float a0, a1, a2, a3, a4, a5, a6, a7;
    a0 = __uint_as_float(u.x << 16); a1 = __uint_as_float(u.x & 0xffff0000u);
    a2 = __uint_as_float(u.y << 16); a3 = __uint_as_float(u.y & 0xffff0000u);
    a4 = __uint_as_float(u.z << 16); a5 = __uint_as_float(u.z & 0xffff0000u);
    a6 = __uint_as_float(u.w << 16); a7 = __uint_as_float(u.w & 0xffff0000u);
    int e0 = roff[node], e1 = roff[node + 1];
    int e = e0;
    for (; e + 16 <= e1; e += 16) GATHER16(h1b)
    for (; e + 4 <= e1; e += 4) GATHER4(h1b)
    for (; e < e1; ++e) {
        int s = __builtin_nontemporal_load(&csr[e]);
        uint4 v = h1b[(size_t)s * 4 + j];
        ACC8(v)
    }
    float d = dis[node];
    float4 bb0 = *(const float4*)&b1[j * 8];
    float4 bb1 = *(const float4*)&b1[j * 8 + 4];
    float r0 = fmaxf(a0 * d + bb0.x, 0.f) * d, r1 = fmaxf(a1 * d + bb0.y, 0.f) * d;
    float r2 = fmaxf(a2 * d + bb0.z, 0.f) * d, r3 = fmaxf(a3 * d + bb0.w, 0.f) * d;
    float r4 = fmaxf(a4 * d + bb1.x, 0.f) * d, r5 = fmaxf(a5 * d + bb1.y, 0.f) * d;
    float r6 = fmaxf(a6 * d + bb1.z, 0.f) * d, r7 = fmaxf(a7 * d + bb1.w, 0.f) * d;
    uint4 o;
    o.x = bf16rne(r0) | (bf16rne(r1) << 16);
    o.y = bf16rne(r2) | (bf16rne(r3) << 16);
    o.z = bf16rne(r4) | (bf16rne(r5) << 16);
    o.w = bf16rne(r6) | (bf16rne(r7) << 16);
    t_out[(size_t)node * 4 + j] = o;
}

// --- agg2 + gemm2 FUSED: s2 = dis*(self + sum t[src]) staged in LDS,
//     then out[node] = s2 @ W2 + b2; unroll-16 gather ---
__global__ __launch_bounds__(256) void k_agg2f(const uint4* __restrict__ tb,
                                               const int* __restrict__ roff,
                                               const int* __restrict__ csr,
                                               const float* __restrict__ dis,
                                               const float* __restrict__ W2,
                                               const float* __restrict__ b2,
                                               float* __restrict__ out, int N) {
    __shared__ float sW[HID * EMB];   // 8 KB
    __shared__ float sS[64][33];      // 8.25 KB, padded stride (bank-clean)
    const int tid = threadIdx.x;
    for (int i = tid; i < HID * EMB; i += 256) sW[i] = W2[i];
    int tt = blockIdx.x * 256 + tid;
    int node = tt >> 2;
    int j = tt & 3;
    int nl = tid >> 2;                // node-local row 0..63
    bool valid = (node < N);
    if (valid) {
        uint4 u = tb[(size_t)node * 4 + j];     // self-loop
        float a0, a1, a2, a3, a4, a5, a6, a7;
        a0 = __uint_as_float(u.x << 16); a1 = __uint_as_float(u.x & 0xffff0000u);
        a2 = __uint_as_float(u.y << 16); a3 = __uint_as_float(u.y & 0xffff0000u);
        a4 = __uint_as_float(u.z << 16); a5 = __uint_as_float(u.z & 0xffff0000u);
        a6 = __uint_as_float(u.w << 16); a7 = __uint_as_float(u.w & 0xffff0000u);
        int e0 = roff[node], e1 = roff[node + 1];
        int e = e0;
        for (; e + 16 <= e1; e += 16) GATHER16(tb)
        for (; e + 4 <= e1; e += 4) GATHER4(tb)
        for (; e < e1; ++e) {
            int s = __builtin_nontemporal_load(&csr[e]);
            uint4 v = tb[(size_t)s * 4 + j];
            ACC8(v)
        }
        float d = dis[node];
        float* sp = &sS[nl][j * 8];
        sp[0] = a0 * d; sp[1] = a1 * d; sp[2] = a2 * d; sp[3] = a3 * d;
        sp[4] = a4 * d; sp[5] = a5 * d; sp[6] = a6 * d; sp[7] = a7 * d;
    }
    __syncthreads();
    if (valid) {
        const int cb = j * 16;   // this lane's 16 output channels
        float4 c0 = *(const float4*)&b2[cb];
        float4 c1 = *(const float4*)&b2[cb + 4];
        float4 c2 = *(const float4*)&b2[cb + 8];
        float4 c3 = *(const float4*)&b2[cb + 12];
#pragma unroll 8
        for (int k = 0; k < HID; ++k) {
            float s = sS[nl][k];
            const float4* w = (const float4*)&sW[k * EMB + cb];
            float4 w0 = w[0], w1 = w[1], w2 = w[2], w3 = w[3];
            c0.x += s * w0.x; c0.y += s * w0.y; c0.z += s * w0.z; c0.w += s * w0.w;
            c1.x += s * w1.x; c1.y += s * w1.y; c1.z += s * w1.z; c1.w += s * w1.w;
            c2.x += s * w2.x; c2.y += s * w2.y; c2.z += s * w2.z; c2.w += s * w2.w;
            c3.x += s * w3.x; c3.y += s * w3.y; c3.z += s * w3.z; c3.w += s * w3.w;
        }
        float* op = &out[(size_t)node * EMB + cb];
        vf4 o0, o1, o2, o3;
        o0.x = c0.x; o0.y = c0.y; o0.z = c0.z; o0.w = c0.w;
        o1.x = c1.x; o1.y = c1.y; o1.z = c1.z; o1.w = c1.w;
        o2.x = c2.x; o2.y = c2.y; o2.z = c2.z; o2.w = c2.w;
        o3.x = c3.x; o3.y = c3.y; o3.z = c3.z; o3.w = c3.w;
        __builtin_nontemporal_store(o0, (vf4*)op);
        __builtin_nontemporal_store(o1, (vf4*)(op + 4));
        __builtin_nontemporal_store(o2, (vf4*)(op + 8));
        __builtin_nontemporal_store(o3, (vf4*)(op + 12));
    }
}

extern "C" void kernel_launch(void* const* d_in, const int* in_sizes, int n_in,
                              void* d_out, int out_size, void* d_ws, size_t ws_size,
                              hipStream_t stream) {
    const float* x  = (const float*)d_in[0];
    const void*  ei = d_in[1];
    const float* W1 = (const float*)d_in[2];
    const float* b1 = (const float*)d_in[3];
    const float* W2 = (const float*)d_in[4];
    const float* b2 = (const float*)d_in[5];
    float* out = (float*)d_out;

    const int N = in_sizes[0] / NF;              // 100000
    const int E = in_sizes[1] / 2;               // 3200000
    const int nbuk = (N + BNODES - 1) >> BSHIFT; // 98

    char* ws = (char*)d_ws;
    size_t off = 0;
    auto take = [&](size_t bytes) -> void* {
        void* p = ws + off;
        off += (bytes + 255) & ~(size_t)255;
        return p;
    };
    // zeroed region first (single memset)
    int* cnt_ovf = (int*)take((size_t)N * 4);
    int* bcur8   = (int*)take((size_t)NBUKMAX * 8 * 4);
    int* ovfcnt  = (int*)take(4);
    size_t zbytes = off;
    // rest
    int*                bbase  = (int*)take((size_t)NBUKMAX * 4);
    int*                roff   = (int*)take((size_t)(N + 1) * 4);
    int*                cursor = (int*)take((size_t)N * 4);
    float*              dis    = (float*)take((size_t)N * 4);
    int*                histc  = (int*)take((size_t)NBUKMAX * CHUNKS * BNODES * 4);
    unsigned*           pairs  = (unsigned*)take((size_t)nbuk * CAP * 4);
    unsigned long long* ovf    = (unsigned long long*)take((size_t)E * 8);
    int*                csr    = (int*)take((size_t)E * 4);
    unsigned*           h1b    = (unsigned*)take((size_t)N * HID * 2);
    unsigned*           tb     = (unsigned*)take((size_t)N * HID * 2);

    (void)hipMemsetAsync(cnt_ovf, 0, zbytes, stream);

    const int gridBC = ((nbuk + 7) / 8) * 64;
    const int gridAgg = (int)(((size_t)N * 4 + 255) / 256);

    k_part<<<(E + TILE - 1) / TILE, 512, 0, stream>>>(ei, pairs, bcur8, cnt_ovf,
                                                      ovf, ovfcnt, E, nbuk);
    k_bscan<<<1, 128, 0, stream>>>(bcur8, bbase, roff, nbuk, E, N);
    k_hist<<<gridBC, 512, 0, stream>>>(pairs, bcur8, histc, nbuk);
    k_nscan<<<nbuk, 256, 0, stream>>>(histc, bbase, cnt_ovf, roff, cursor, dis, N);
    k_scat2<<<gridBC, 512, 0, stream>>>(pairs, bcur8, histc, csr, ovf, ovfcnt,
                                        cursor, nbuk);

    k_gemm1<<<(N + 31) / 32, 256, 0, stream>>>(x, W1, dis, h1b, N);
    k_agg1<<<gridAgg, 256, 0, stream>>>((const uint4*)h1b, roff, csr, dis, b1,
                                        (uint4*)tb, N);
    k_agg2f<<<gridAgg, 256, 0, stream>>>((const uint4*)tb, roff, csr, dis,
                                         W2, b2, out, N);
}